// Round 3
// baseline (1694.617 us; speedup 1.0000x reference)
//
#include <hip/hip_runtime.h>
#include <stdint.h>

#define EPSF 1e-8f
#define KT 4160

typedef float  f32x4  __attribute__((ext_vector_type(4)));
typedef __bf16 bf16x8 __attribute__((ext_vector_type(8)));
typedef __bf16 bf16x4 __attribute__((ext_vector_type(4)));

// ---------------- workspace layout ----------------
// fp32 region (element offsets)
constexpr size_t oP    = 0;                     // P   [8192*64] (summed)
constexpr size_t oW    = oP  + 8192*64;         // W   [4096*64] (summed)
constexpr size_t oG    = oW  + 4096*64;         // Gram[64*64]
constexpr size_t oM1   = oG  + 64*64;           // M1  [64*4096]
constexpr size_t oScal = oM1 + 64*4096;         // 4 u32: amax_w, amax_u, amax_v, amax_r
constexpr size_t nZeroA= 64*64 + 64*4096 + 4;   // zero G+M1+scal (contiguous from oG)
constexpr size_t oS    = oScal + 4;             // 64
constexpr size_t oLinv = oS + 64;               // 64*64
constexpr size_t oV    = oLinv + 64*64;         // (unused, kept for layout stability)
constexpr size_t oU    = oV + 4096*64;          // Ub [8192*64]
constexpr size_t endF32= oU + 8192*64;
constexpr size_t bfByte= ((endF32*4 + 255)/256)*256;
// bf16 region (element offsets)
constexpr size_t oVq   = 0;                     // Vq [64*4096]
constexpr size_t oA    = oVq + 64*4096;         // A = [Rq | Uq]  [8192*4160]
constexpr size_t oB    = oA + (size_t)8192*4160;// B = [Wq | M2T] [4096*4160]
constexpr size_t oVcT  = oB + (size_t)4096*4160;// VcT h/m/l 3x[64*4096]
constexpr size_t oUT   = oVcT + 3*(size_t)64*4096;   // UT h/m/l 3x[64*8192]
constexpr size_t oUhl  = oUT + 3*(size_t)64*8192;    // U h/l 2x[8192*64]
constexpr size_t oKVT  = oUhl + 2*(size_t)8192*64;   // KVT h/l 2x[4096*64]
constexpr size_t endBF = oKVT + 2*(size_t)4096*64;
constexpr size_t WS_NEED = bfByte + endBF*2;
// scratch partials (fp32) aliased into the Aq region: dead until k_qu / k_res m1,
// last read by k_colnorm#2 which precedes both. P8 16 MB + W8 8 MB < Aq 68 MB.

// ---------------- fp4 e2m1 helpers ----------------
__device__ __forceinline__ float qlevel(float a){
  if (a <= 0.25f) return 0.0f;
  if (a <= 0.75f) return 0.5f;
  if (a <= 1.25f) return 1.0f;
  if (a <= 1.75f) return 1.5f;
  if (a <= 2.5f)  return 2.0f;
  if (a <= 3.5f)  return 3.0f;
  if (a <= 5.0f)  return 4.0f;
  return 6.0f;
}
__device__ __forceinline__ float qgrid(float v, float s){
  float y = v / s;
  float l = qlevel(fabsf(y));
  return y < 0.0f ? -l : l;
}

// ---------------- utility ----------------
__global__ void k_zero(float* p, int n){
  for (int i = blockIdx.x*blockDim.x + threadIdx.x; i < n; i += gridDim.x*blockDim.x)
    p[i] = 0.0f;
}

__global__ void k_amax4(const float4* __restrict__ x, int n4, unsigned* __restrict__ out){
  float m = 0.f;
  for (int i = blockIdx.x*blockDim.x + threadIdx.x; i < n4; i += gridDim.x*blockDim.x){
    float4 v = x[i];
    m = fmaxf(m, fmaxf(fmaxf(fabsf(v.x), fabsf(v.y)), fmaxf(fabsf(v.z), fabsf(v.w))));
  }
  for (int o = 32; o > 0; o >>= 1) m = fmaxf(m, __shfl_down(m, o, 64));
  __shared__ float sm[4];
  int lane = threadIdx.x & 63, w = threadIdx.x >> 6;
  if (lane == 0) sm[w] = m;
  __syncthreads();
  if (threadIdx.x == 0)
    atomicMax(out, __float_as_uint(fmaxf(fmaxf(sm[0],sm[1]), fmaxf(sm[2],sm[3]))));
}

// ---------------- P8[by] = x @ Vc partial  via 3-word-split bf16 MFMA  grid(64,8) ----------------
// Partial stores (no atomics); k_gram folds the 8-way sum.
__global__ __launch_bounds__(256) void k_gv(
    float* __restrict__ P8, const float* __restrict__ x,
    const __bf16* __restrict__ Bh, const __bf16* __restrict__ Bm, const __bf16* __restrict__ Bl){
  int m0 = blockIdx.x * 128;
  int d0 = blockIdx.y * 512;
  size_t pb = (size_t)blockIdx.y * 8192 * 64;
  int lane = threadIdx.x & 63, wave = threadIdx.x >> 6;
  int kgrp = lane >> 4, lrow = lane & 15;
  f32x4 acc[2][4] = {};
  for (int dc = d0; dc < d0 + 512; dc += 32){
    bf16x8 ah[2], am[2], al[2];
    #pragma unroll
    for (int f = 0; f < 2; f++){
      const float* g = x + (size_t)(m0 + wave*32 + f*16 + lrow)*4096 + dc + kgrp*8;
      float4 a = *(const float4*)g;
      float4 b = *(const float4*)(g + 4);
      float v[8] = {a.x,a.y,a.z,a.w,b.x,b.y,b.z,b.w};
      #pragma unroll
      for (int j = 0; j < 8; j++){
        __bf16 h = (__bf16)v[j];
        float r1 = v[j] - (float)h;
        __bf16 md = (__bf16)r1;
        float r2 = r1 - (float)md;
        ah[f][j] = h; am[f][j] = md; al[f][j] = (__bf16)r2;
      }
    }
    #pragma unroll
    for (int n = 0; n < 4; n++){
      size_t bo = (size_t)(n*16 + lrow)*4096 + dc + kgrp*8;
      bf16x8 bh = *(const bf16x8*)(Bh + bo);
      bf16x8 bm = *(const bf16x8*)(Bm + bo);
      bf16x8 bl = *(const bf16x8*)(Bl + bo);
      #pragma unroll
      for (int f = 0; f < 2; f++){
        acc[f][n] = __builtin_amdgcn_mfma_f32_16x16x32_bf16(ah[f], bh, acc[f][n],0,0,0);
        acc[f][n] = __builtin_amdgcn_mfma_f32_16x16x32_bf16(ah[f], bm, acc[f][n],0,0,0);
        acc[f][n] = __builtin_amdgcn_mfma_f32_16x16x32_bf16(am[f], bh, acc[f][n],0,0,0);
        acc[f][n] = __builtin_amdgcn_mfma_f32_16x16x32_bf16(ah[f], bl, acc[f][n],0,0,0);
        acc[f][n] = __builtin_amdgcn_mfma_f32_16x16x32_bf16(al[f], bh, acc[f][n],0,0,0);
        acc[f][n] = __builtin_amdgcn_mfma_f32_16x16x32_bf16(am[f], bm, acc[f][n],0,0,0);
      }
    }
  }
  #pragma unroll
  for (int f = 0; f < 2; f++)
    #pragma unroll
    for (int n = 0; n < 4; n++)
      #pragma unroll
      for (int r = 0; r < 4; r++)
        P8[pb + (size_t)(m0 + wave*32 + f*16 + kgrp*4 + r)*64 + n*16 + lrow] = acc[f][n][r];
}

// ---------------- W8[by] = x^T @ U partial  grid(64,8) ----------------
__global__ __launch_bounds__(256) void k_gtu(
    float* __restrict__ W8, const float* __restrict__ x,
    const __bf16* __restrict__ Bh, const __bf16* __restrict__ Bm, const __bf16* __restrict__ Bl){
  int d0 = blockIdx.x * 64;
  int m0 = blockIdx.y * 1024;
  size_t wb = (size_t)blockIdx.y * 4096 * 64;
  int lane = threadIdx.x & 63, wave = threadIdx.x >> 6;
  int kgrp = lane >> 4, lrow = lane & 15;
  int dcol = d0 + wave*16 + lrow;
  f32x4 acc[4] = {};
  for (int mc = m0; mc < m0 + 1024; mc += 32){
    bf16x8 ah, am, al;
    int mb = mc + kgrp*8;
    #pragma unroll
    for (int j = 0; j < 8; j++){
      float v = x[(size_t)(mb + j)*4096 + dcol];
      __bf16 h = (__bf16)v;
      float r1 = v - (float)h;
      __bf16 md = (__bf16)r1;
      float r2 = r1 - (float)md;
      ah[j] = h; am[j] = md; al[j] = (__bf16)r2;
    }
    #pragma unroll
    for (int n = 0; n < 4; n++){
      size_t bo = (size_t)(n*16 + lrow)*8192 + mc + kgrp*8;
      bf16x8 bh = *(const bf16x8*)(Bh + bo);
      bf16x8 bm = *(const bf16x8*)(Bm + bo);
      bf16x8 bl = *(const bf16x8*)(Bl + bo);
      acc[n] = __builtin_amdgcn_mfma_f32_16x16x32_bf16(ah, bh, acc[n],0,0,0);
      acc[n] = __builtin_amdgcn_mfma_f32_16x16x32_bf16(ah, bm, acc[n],0,0,0);
      acc[n] = __builtin_amdgcn_mfma_f32_16x16x32_bf16(am, bh, acc[n],0,0,0);
      acc[n] = __builtin_amdgcn_mfma_f32_16x16x32_bf16(ah, bl, acc[n],0,0,0);
      acc[n] = __builtin_amdgcn_mfma_f32_16x16x32_bf16(al, bh, acc[n],0,0,0);
      acc[n] = __builtin_amdgcn_mfma_f32_16x16x32_bf16(am, bm, acc[n],0,0,0);
    }
  }
  #pragma unroll
  for (int n = 0; n < 4; n++)
    #pragma unroll
    for (int r = 0; r < 4; r++)
      W8[wb + (size_t)(d0 + wave*16 + kgrp*4 + r)*64 + n*16 + lrow] = acc[n][r];
}

// ---------------- Gram += Pchunk^T Pchunk (folds 8-way partial sum; writes Psum) grid 64 ----------------
__global__ void k_gram(const float* __restrict__ P8, float* __restrict__ Psum,
                       float* __restrict__ Gram){
  __shared__ float Pt[128][65];
  int m0 = blockIdx.x * 128;
  int t = threadIdx.x;
  for (int i = 0; i < 32; i++){
    int idx = i*256 + t; int r = idx >> 6, c = idx & 63;
    float s = 0.f;
    #pragma unroll
    for (int b = 0; b < 8; b++)
      s += P8[((size_t)b*8192 + m0 + r)*64 + c];
    Pt[r][c] = s;
    Psum[(size_t)(m0+r)*64 + c] = s;
  }
  __syncthreads();
  int ti = t >> 4, tj = t & 15;
  float acc[4][4] = {};
  for (int r = 0; r < 128; r++){
    float a[4], b[4];
    #pragma unroll
    for (int q = 0; q < 4; q++) a[q] = Pt[r][ti*4+q];
    #pragma unroll
    for (int q = 0; q < 4; q++) b[q] = Pt[r][tj*4+q];
    #pragma unroll
    for (int xx = 0; xx < 4; xx++)
      #pragma unroll
      for (int y = 0; y < 4; y++) acc[xx][y] += a[xx]*b[y];
  }
  for (int xx = 0; xx < 4; xx++)
    for (int y = 0; y < 4; y++)
      atomicAdd(&Gram[(ti*4+xx)*64 + tj*4+y], acc[xx][y]);
}

// ---------------- fp64 Cholesky of Gram + lower-tri inverse ----------------
__global__ void k_cholinv(const float* __restrict__ Gram, float* __restrict__ Linv){
  __shared__ double A[64][64];
  __shared__ double Li[64][64];
  int t = threadIdx.x;
  for (int j = 0; j < 64; j++){ A[t][j] = (double)Gram[t*64+j]; Li[t][j] = 0.0; }
  __syncthreads();
  for (int k = 0; k < 64; k++){
    if (t == k) A[k][k] = sqrt(A[k][k]);
    __syncthreads();
    if (t > k) A[t][k] /= A[k][k];
    __syncthreads();
    if (t > k){
      double aik = A[t][k];
      for (int j = k+1; j <= t; j++) A[t][j] -= aik * A[j][k];
    }
    __syncthreads();
  }
  for (int i = t; i < 64; i++){
    double s = (i == t) ? 1.0 : 0.0;
    for (int p = t; p < i; p++) s -= A[i][p] * Li[p][t];
    Li[i][t] = s / A[i][i];
  }
  __syncthreads();
  for (int j = 0; j < 64; j++) Linv[t*64+j] = (float)Li[t][j];
}

// ---------------- U = P @ Linv^T   grid 128 ----------------
__global__ void k_applyq(float* __restrict__ U, const float* __restrict__ P,
                         const float* __restrict__ Linv){
  __shared__ float Pt[64][65];
  __shared__ float Lt[64][65];
  int m0 = blockIdx.x * 64;
  int t = threadIdx.x;
  for (int i = 0; i < 16; i++){
    int idx = i*256 + t; int r = idx >> 6, c = idx & 63;
    Pt[r][c] = P[(size_t)(m0+r)*64 + c];
    Lt[r][c] = Linv[r*64 + c];
  }
  __syncthreads();
  int tm = t >> 4, tj = t & 15;
  float acc[4][4] = {};
  for (int i = 0; i < 64; i++){
    float p[4], lv[4];
    #pragma unroll
    for (int a = 0; a < 4; a++) p[a]  = Pt[tm*4+a][i];
    #pragma unroll
    for (int b = 0; b < 4; b++) lv[b] = Lt[tj*4+b][i];
    #pragma unroll
    for (int a = 0; a < 4; a++)
      #pragma unroll
      for (int b = 0; b < 4; b++) acc[a][b] += p[a]*lv[b];
  }
  for (int a = 0; a < 4; a++)
    for (int b = 0; b < 4; b++)
      U[(size_t)(m0+tm*4+a)*64 + tj*4+b] = acc[a][b];
}

// ---------------- column norms: fold 8-way W partial sum, write Wsum + cn  grid 64 ----------------
__global__ void k_colnorm(const float* __restrict__ W8, float* __restrict__ Wsum,
                          float* __restrict__ cn){
  int k = blockIdx.x;
  float s = 0.f;
  for (int d = threadIdx.x; d < 4096; d += 256){
    float v = 0.f;
    #pragma unroll
    for (int b = 0; b < 8; b++)
      v += W8[((size_t)b*4096 + d)*64 + k];
    Wsum[(size_t)d*64 + k] = v;
    s += v*v;
  }
  for (int o = 32; o > 0; o >>= 1) s += __shfl_down(s, o, 64);
  __shared__ float sm[4];
  int lane = threadIdx.x & 63, w = threadIdx.x >> 6;
  if (lane == 0) sm[w] = s;
  __syncthreads();
  if (threadIdx.x == 0) cn[k] = sqrtf(sm[0]+sm[1]+sm[2]+sm[3]);
}

// KVT[d][k] = S*Vn (bf16 h/l); amax_v of Vn = W/(S+EPS)   grid 1024
__global__ void k_kv(__bf16* __restrict__ Kh, __bf16* __restrict__ Kl,
                     const float* __restrict__ W, const float* __restrict__ S,
                     unsigned* __restrict__ amaxv){
  int i = blockIdx.x*256 + threadIdx.x;
  int k = i & 63, d = i >> 6;
  float s = S[k];
  float vn = W[i] / (s + EPSF);
  float kv = s * vn;
  __bf16 h = (__bf16)kv;
  Kh[(size_t)d*64 + k] = h;
  Kl[(size_t)d*64 + k] = (__bf16)(kv - (float)h);
  float m = fabsf(vn);
  for (int o = 32; o > 0; o >>= 1) m = fmaxf(m, __shfl_down(m, o, 64));
  __shared__ float sm[4];
  int lane = threadIdx.x & 63, w = threadIdx.x >> 6;
  if (lane == 0) sm[w] = m;
  __syncthreads();
  if (threadIdx.x == 0)
    atomicMax(amaxv, __float_as_uint(fmaxf(fmaxf(sm[0],sm[1]), fmaxf(sm[2],sm[3]))));
}

// ---------------- transpose+3-split prep: Vc[4096,64] -> VcT h/m/l [64,4096]  grid 64 ----------------
__global__ void k_prep_vct(const float* __restrict__ Vc, __bf16* __restrict__ Th,
                           __bf16* __restrict__ Tm, __bf16* __restrict__ Tl){
  __shared__ float Vt[64][65];
  int d0 = blockIdx.x * 64;
  int t = threadIdx.x;
  for (int i = 0; i < 16; i++){
    int idx = i*256 + t; int r = idx >> 6, c = idx & 63;
    Vt[r][c] = Vc[(size_t)(d0 + r)*64 + c];
  }
  __syncthreads();
  for (int i = 0; i < 16; i++){
    int idx = i*256 + t; int k = idx >> 6, dd = idx & 63;
    float v = Vt[dd][k];
    __bf16 h = (__bf16)v;
    float r1 = v - (float)h;
    __bf16 md = (__bf16)r1;
    float r2 = r1 - (float)md;
    size_t o = (size_t)k*4096 + d0 + dd;
    Th[o] = h; Tm[o] = md; Tl[o] = (__bf16)r2;
  }
}

// normalized variant: V = W/(cn+EPS) computed on the fly (V never materialized)  grid 64
__global__ void k_prep_vctn(const float* __restrict__ W, const float* __restrict__ cn,
                            __bf16* __restrict__ Th, __bf16* __restrict__ Tm,
                            __bf16* __restrict__ Tl){
  __shared__ float Vt[64][65];
  __shared__ float cs[64];
  int d0 = blockIdx.x * 64;
  int t = threadIdx.x;
  if (t < 64) cs[t] = cn[t];
  __syncthreads();
  for (int i = 0; i < 16; i++){
    int idx = i*256 + t; int r = idx >> 6, c = idx & 63;
    Vt[r][c] = W[(size_t)(d0 + r)*64 + c] / (cs[c] + EPSF);
  }
  __syncthreads();
  for (int i = 0; i < 16; i++){
    int idx = i*256 + t; int k = idx >> 6, dd = idx & 63;
    float v = Vt[dd][k];
    __bf16 h = (__bf16)v;
    float r1 = v - (float)h;
    __bf16 md = (__bf16)r1;
    float r2 = r1 - (float)md;
    size_t o = (size_t)k*4096 + d0 + dd;
    Th[o] = h; Tm[o] = md; Tl[o] = (__bf16)r2;
  }
}

// prep U: Ub[8192,64] -> U h/l [8192,64] + UT h/m/l [64,8192]   grid 128
__global__ void k_prep_u(const float* __restrict__ Ub, __bf16* __restrict__ Uh, __bf16* __restrict__ Ul,
                         __bf16* __restrict__ Th, __bf16* __restrict__ Tm, __bf16* __restrict__ Tl){
  __shared__ float Ut[64][65];
  int m0 = blockIdx.x * 64;
  int t = threadIdx.x;
  for (int i = 0; i < 16; i++){
    int idx = i*256 + t; int r = idx >> 6, c = idx & 63;
    float v = Ub[(size_t)(m0 + r)*64 + c];
    Ut[r][c] = v;
    __bf16 h = (__bf16)v;
    Uh[(size_t)(m0+r)*64 + c] = h;
    Ul[(size_t)(m0+r)*64 + c] = (__bf16)(v - (float)h);
  }
  __syncthreads();
  for (int i = 0; i < 16; i++){
    int idx = i*256 + t; int k = idx >> 6, mm = idx & 63;
    float v = Ut[mm][k];
    __bf16 h = (__bf16)v;
    float r1 = v - (float)h;
    __bf16 md = (__bf16)r1;
    float r2 = r1 - (float)md;
    size_t o = (size_t)k*8192 + m0 + mm;
    Th[o] = h; Tm[o] = md; Tl[o] = (__bf16)r2;
  }
}

// ---------------- quantize weight -> Bq[:, :4096]  (float4)  grid 16384 ----------------
__global__ void k_qw(__bf16* __restrict__ Bq, const float* __restrict__ w,
                     const unsigned* __restrict__ amaxw){
  float s = fmaxf(__uint_as_float(*amaxw) / 6.0f, EPSF);
  int i = blockIdx.x*256 + threadIdx.x;          // 4.19M groups of 4
  int n = i >> 10, d = (i & 1023)*4;
  float4 v = *(const float4*)(w + (size_t)n*4096 + d);
  bf16x4 o;
  o[0] = (__bf16)qgrid(v.x, s); o[1] = (__bf16)qgrid(v.y, s);
  o[2] = (__bf16)qgrid(v.z, s); o[3] = (__bf16)qgrid(v.w, s);
  *(bf16x4*)(Bq + (size_t)n*4160 + d) = o;
}

// ---------------- quantize U -> Aq[:, 4096:4160]  grid 2048 ----------------
__global__ void k_qu(__bf16* __restrict__ Aq, const float* __restrict__ U,
                     const unsigned* __restrict__ amaxu){
  float s = fmaxf(__uint_as_float(*amaxu) / 6.0f, EPSF);
  int i = blockIdx.x*256 + threadIdx.x;
  int m = i >> 6, k = i & 63;
  Aq[(size_t)m*4160 + 4096 + k] = (__bf16)qgrid(U[i], s);
}

// ---------------- quantize V -> Vq[k][d] (LDS transpose; V = W/(S+EPS) on the fly)  grid 64 ----------------
__global__ void k_qv(__bf16* __restrict__ Vq, const float* __restrict__ W,
                     const float* __restrict__ S, const unsigned* __restrict__ amaxv){
  __shared__ float Vt[64][65];
  __shared__ float cs[64];
  float s = fmaxf(__uint_as_float(*amaxv)/6.0f, EPSF);
  int d0 = blockIdx.x * 64;
  int t = threadIdx.x;
  if (t < 64) cs[t] = S[t];
  __syncthreads();
  for (int i = 0; i < 16; i++){
    int idx = i*256 + t; int r = idx >> 6, c = idx & 63;
    Vt[r][c] = W[(size_t)(d0 + r)*64 + c] / (cs[c] + EPSF);
  }
  __syncthreads();
  for (int i = 0; i < 16; i++){
    int idx = i*256 + t; int k = idx >> 6, dd = idx & 63;
    Vq[(size_t)k*4096 + d0 + dd] = (__bf16)qgrid(Vt[dd][k], s);
  }
}

// ---------------- residual: ker = U@KV via 2-split MFMA; amax or quantize  grid(128,32) ----------------
__global__ __launch_bounds__(256) void k_res(
    const float* __restrict__ x, const __bf16* __restrict__ Uh, const __bf16* __restrict__ Ul,
    const __bf16* __restrict__ Kh, const __bf16* __restrict__ Kl,
    unsigned* __restrict__ amaxr, __bf16* __restrict__ Aq, int mode){
  int m0 = blockIdx.x * 64, n0 = blockIdx.y * 128;
  int lane = threadIdx.x & 63, wave = threadIdx.x >> 6;
  int kgrp = lane >> 4, lrow = lane & 15;
  int mrow = m0 + wave*16 + lrow;
  f32x4 acc[8] = {};
  #pragma unroll
  for (int ks = 0; ks < 2; ks++){
    size_t ao = (size_t)mrow*64 + ks*32 + kgrp*8;
    bf16x8 uh = *(const bf16x8*)(Uh + ao);
    bf16x8 ul = *(const bf16x8*)(Ul + ao);
    #pragma unroll
    for (int n = 0; n < 8; n++){
      size_t bo = (size_t)(n0 + n*16 + lrow)*64 + ks*32 + kgrp*8;
      bf16x8 kh = *(const bf16x8*)(Kh + bo);
      bf16x8 kl = *(const bf16x8*)(Kl + bo);
      acc[n] = __builtin_amdgcn_mfma_f32_16x16x32_bf16(uh, kh, acc[n],0,0,0);
      acc[n] = __builtin_amdgcn_mfma_f32_16x16x32_bf16(uh, kl, acc[n],0,0,0);
      acc[n] = __builtin_amdgcn_mfma_f32_16x16x32_bf16(ul, kh, acc[n],0,0,0);
    }
  }
  int mb = m0 + wave*16 + kgrp*4;
  if (mode == 0){
    float mx = 0.f;
    #pragma unroll
    for (int n = 0; n < 8; n++){
      int c = n0 + n*16 + lrow;
      #pragma unroll
      for (int r = 0; r < 4; r++)
        mx = fmaxf(mx, fabsf(x[(size_t)(mb + r)*4096 + c] - acc[n][r]));
    }
    for (int o = 32; o > 0; o >>= 1) mx = fmaxf(mx, __shfl_down(mx, o, 64));
    __shared__ float sm[4];
    if (lane == 0) sm[wave] = mx;
    __syncthreads();
    if (threadIdx.x == 0)
      atomicMax(amaxr, __float_as_uint(fmaxf(fmaxf(sm[0],sm[1]), fmaxf(sm[2],sm[3]))));
  } else {
    float s = fmaxf(__uint_as_float(*amaxr)/6.0f, EPSF);
    #pragma unroll
    for (int n = 0; n < 8; n++){
      int c = n0 + n*16 + lrow;
      #pragma unroll
      for (int r = 0; r < 4; r++)
        Aq[(size_t)(mb + r)*4160 + c] =
          (__bf16)qgrid(x[(size_t)(mb + r)*4096 + c] - acc[n][r], s);
    }
  }
}

// ---------------- M1 += Vq @ Wq^T  (exact bf16 MFMA)  grid(64,8) ----------------
__global__ __launch_bounds__(256) void k_m1(
    float* __restrict__ M1g, const __bf16* __restrict__ Vq, const __bf16* __restrict__ Bq){
  int n0 = blockIdx.x * 64;
  int k0 = blockIdx.y * 512;
  int lane = threadIdx.x & 63, wave = threadIdx.x >> 6;
  int kgrp = lane >> 4, lrow = lane & 15;
  int nrow = n0 + wave*16 + lrow;
  f32x4 acc[4] = {};
  for (int kc = k0; kc < k0 + 512; kc += 32){
    bf16x8 fb = *(const bf16x8*)(Bq + (size_t)nrow*4160 + kc + kgrp*8);
    #pragma unroll
    for (int mt = 0; mt < 4; mt++){
      bf16x8 fa = *(const bf16x8*)(Vq + (size_t)(mt*16 + lrow)*4096 + kc + kgrp*8);
      acc[mt] = __builtin_amdgcn_mfma_f32_16x16x32_bf16(fa, fb, acc[mt],0,0,0);
    }
  }
  #pragma unroll
  for (int mt = 0; mt < 4; mt++)
    #pragma unroll
    for (int r = 0; r < 4; r++)
      atomicAdd(&M1g[(size_t)(mt*16 + kgrp*4 + r)*4096 + nrow], acc[mt][r]);
}

// ---------------- M2T: Bq[:, 4096:4160] = M1[k][n] * su*sv*S[k]/sr  grid 1024 ----------------
__global__ void k_m2t(__bf16* __restrict__ Bq, const float* __restrict__ M1g,
                      const float* __restrict__ S, const unsigned* __restrict__ scal){
  float su = fmaxf(__uint_as_float(scal[1])/6.0f, EPSF);
  float sv = fmaxf(__uint_as_float(scal[2])/6.0f, EPSF);
  float sr = fmaxf(__uint_as_float(scal[3])/6.0f, EPSF);
  int i = blockIdx.x*256 + threadIdx.x;
  int n = i >> 6, k = i & 63;
  float v = M1g[(size_t)k*4096 + n] * (su * sv * S[k] / sr);
  Bq[(size_t)n*4160 + 4096 + k] = (__bf16)v;
}

// ---------------- main bf16 MFMA GEMM: out = (A @ B^T)*sr*sw + bias ----------------
// 256x256 tile, BK=32, 512 threads (8 waves, 2Mx4N), 4-deep LDS ring (128 KiB).
// T3+T4 counted vmcnt(8) + builtin barriers; T5 setprio; T1 bijective XCD-chunked
// swizzle (512 blocks, 64/XCD, 2 B-panels per XCD ~ fits its 4 MiB L2).
// STAGE issued before the ds_read burst; fb read before fa so the first MFMA
// depends on 5 lgkm events, not 9.
__global__ __launch_bounds__(512, 2)
void k_gemm(float* __restrict__ out, const __bf16* __restrict__ A,
            const __bf16* __restrict__ B, const float* __restrict__ bias,
            const unsigned* __restrict__ scal){
  __shared__ __align__(16) __bf16 As[4*8192];   // 4 ring slots x 128 packed rows x 64 el
  __shared__ __align__(16) __bf16 Bs[4*8192];
  // T1: bid -> (xcd, idx) -> wg; within an XCD's 64-block chunk, 32 blocks share a B-panel.
  const int bid = blockIdx.y * gridDim.x + blockIdx.x;   // 0..511
  const int wg  = (bid & 7) * 64 + (bid >> 3);
  const int m0 = (wg & 31) * 256, n0 = (wg >> 5) * 256;
  const int tid = threadIdx.x;
  const int lane = tid & 63, wave = tid >> 6;
  const int wrow = wave >> 2, wcol = wave & 3;     // 2 x 4 wave grid
  const int kg = lane >> 4, lr = lane & 15;
  f32x4 acc[8][4] = {};

  auto STAGE = [&](int tt){
    __bf16* as = &As[(tt & 3) * 8192];
    __bf16* bs = &Bs[(tt & 3) * 8192];
    const int kt = tt * 32;
    #pragma unroll
    for (int q = 0; q < 2; q++){
      int idx = q * 512 + tid;                 // 1024 16B-slots per matrix
      int rp  = idx >> 3;                      // packed LDS row 0..127
      int sp  = (idx & 7) ^ (rp & 7);          // unswizzled slot
      int grow = rp * 2 + (sp >> 2);           // global tile row 0..255
      int gcol = (sp & 3) * 8;                 // global k element 0..24
      const __bf16* ga = A + (size_t)(m0 + grow) * KT + kt + gcol;
      const __bf16* gb = B + (size_t)(n0 + grow) * KT + kt + gcol;
      __bf16* la = as + (size_t)(idx & ~63) * 8;
      __bf16* lb = bs + (size_t)(idx & ~63) * 8;
      __builtin_amdgcn_global_load_lds((const __attribute__((address_space(1))) uint32_t*)ga,
                                       (__attribute__((address_space(3))) uint32_t*)la, 16, 0, 0);
      __builtin_amdgcn_global_load_lds((const __attribute__((address_space(1))) uint32_t*)gb,
                                       (__attribute__((address_space(3))) uint32_t*)lb, 16, 0, 0);
    }
  };

  auto BODY = [&](int t, bool stage){
    if (stage) STAGE(t + 3);                    // slot (t+3)&3: last read at iter t-1, safe
    const __bf16* as = &As[(t & 3) * 8192];
    const __bf16* bs = &Bs[(t & 3) * 8192];
    bf16x8 fa[8], fb[4];
    #pragma unroll
    for (int nf = 0; nf < 4; nf++){
      int row = wcol*64 + nf*16 + lr;
      int rp  = row >> 1;
      int sl  = (((row & 1) << 2) | kg) ^ (rp & 7);
      fb[nf] = *(const bf16x8*)(bs + (size_t)rp*64 + sl*8);
    }
    #pragma unroll
    for (int mf = 0; mf < 8; mf++){
      int row = wrow*128 + mf*16 + lr;
      int rp  = row >> 1;
      int sl  = (((row & 1) << 2) | kg) ^ (rp & 7);
      fa[mf] = *(const bf16x8*)(as + (size_t)rp*64 + sl*8);
    }
    __builtin_amdgcn_s_setprio(1);
    #pragma unroll
    for (int mf = 0; mf < 8; mf++)
      #pragma unroll
      for (int nf = 0; nf < 4; nf++)
        acc[mf][nf] = __builtin_amdgcn_mfma_f32_16x16x32_bf16(fa[mf], fb[nf], acc[mf][nf], 0, 0, 0);
    __builtin_amdgcn_s_setprio(0);
  };

  STAGE(0); STAGE(1); STAGE(2);                // prologue: 3 tiles (12 loads) in flight

  const int NT = KT / 32;                      // 130
  for (int t = 0; t < NT - 2; t++){
    asm volatile("s_waitcnt vmcnt(8)" ::: "memory");
    __builtin_amdgcn_s_barrier();
    BODY(t, t < NT - 3);
  }
  asm volatile("s_waitcnt vmcnt(4)" ::: "memory");
  __builtin_amdgcn_s_barrier();
  BODY(NT - 2, false);
  asm volatile("s_waitcnt vmcnt(0)" ::: "memory");
  __builtin_amdgcn_s_barrier();
  BODY(NT - 1, false);

  float sr = fmaxf(__uint_as_float(scal[3])/6.0f, EPSF);
  float sw = fmaxf(__uint_as_float(scal[0])/6.0f, EPSF);
  float srw = sr * sw;
  #pragma unroll
  for (int nf = 0; nf < 4; nf++){
    int n = n0 + wcol*64 + nf*16 + lr;
    float bv = bias[n];
    #pragma unroll
    for (int mf = 0; mf < 8; mf++){
      int mb = m0 + wrow*128 + mf*16 + 4*kg;
      #pragma unroll
      for (int r = 0; r < 4; r++)
        out[(size_t)(mb + r)*4096 + n] = acc[mf][nf][r]*srw + bv;
    }
  }
}

// ---------------- host side ----------------
extern "C" void kernel_launch(void* const* d_in, const int* in_sizes, int n_in,
                              void* d_out, int out_size, void* d_ws, size_t ws_size,
                              hipStream_t stream){
  const float* x    = (const float*)d_in[0];   // [8192, 4096]
  const float* wt   = (const float*)d_in[1];   // [4096, 4096]
  const float* bias = (const float*)d_in[2];   // [4096]
  const float* V0   = (const float*)d_in[3];   // [4096, 64]
  float* out = (float*)d_out;
  if (ws_size < WS_NEED) return;

  float* F = (float*)d_ws;
  unsigned* scal = (unsigned*)(F + oScal);
  __bf16* BFp = (__bf16*)((char*)d_ws + bfByte);
  __bf16* Vq  = BFp + oVq;
  __bf16* Aq  = BFp + oA;
  __bf16* Bq  = BFp + oB;
  __bf16* VcTh = BFp + oVcT,              *VcTm = VcTh + (size_t)64*4096, *VcTl = VcTm + (size_t)64*4096;
  __bf16* UTh  = BFp + oUT,               *UTm  = UTh + (size_t)64*8192,  *UTl  = UTm + (size_t)64*8192;
  __bf16* Uh   = BFp + oUhl,              *Ul   = Uh + (size_t)8192*64;
  __bf16* KVTh = BFp + oKVT,              *KVTl = KVTh + (size_t)4096*64;
  float *P = F+oP, *W = F+oW, *Gm = F+oG, *M1 = F+oM1, *Sv = F+oS,
        *Li = F+oLinv, *Ub = F+oU;
  // fp32 scratch partials aliased into Aq (dead until k_qu / k_res m1)
  float* P8 = (float*)Aq;                       // 8 x 8192 x 64 = 16 MB
  float* W8 = P8 + (size_t)8*8192*64;           // 8 x 4096 x 64 =  8 MB

  dim3 b256(256);
  k_zero <<<dim3(512),  b256, 0, stream>>>(F + oG, (int)nZeroA);   // Gram+M1+scal
  k_amax4<<<dim3(1024), b256, 0, stream>>>((const float4*)wt, 4194304, scal+0);
  k_qw   <<<dim3(16384), b256, 0, stream>>>(Bq, wt, scal+0);

  // ---- power iteration 1 ----
  k_prep_vct<<<dim3(64),  b256, 0, stream>>>(V0, VcTh, VcTm, VcTl);
  k_gv     <<<dim3(64,8), b256, 0, stream>>>(P8, x, VcTh, VcTm, VcTl);
  k_gram   <<<dim3(64),   b256, 0, stream>>>(P8, P, Gm);
  k_cholinv<<<dim3(1), dim3(64), 0, stream>>>(Gm, Li);
  k_applyq <<<dim3(128),  b256, 0, stream>>>(Ub, P, Li);
  k_prep_u <<<dim3(128),  b256, 0, stream>>>(Ub, Uh, Ul, UTh, UTm, UTl);
  k_gtu    <<<dim3(64,8), b256, 0, stream>>>(W8, x, UTh, UTm, UTl);
  k_colnorm<<<dim3(64),   b256, 0, stream>>>(W8, W, Sv);
  k_prep_vctn<<<dim3(64), b256, 0, stream>>>(W, Sv, VcTh, VcTm, VcTl);

  // ---- power iteration 2 ----
  k_zero   <<<dim3(64),   b256, 0, stream>>>(Gm, 4096);            // Gram only
  k_gv     <<<dim3(64,8), b256, 0, stream>>>(P8, x, VcTh, VcTm, VcTl);
  k_gram   <<<dim3(64),   b256, 0, stream>>>(P8, P, Gm);
  k_cholinv<<<dim3(1), dim3(64), 0, stream>>>(Gm, Li);
  k_applyq <<<dim3(128),  b256, 0, stream>>>(Ub, P, Li);
  k_prep_u <<<dim3(128),  b256, 0, stream>>>(Ub, Uh, Ul, UTh, UTm, UTl);
  k_gtu    <<<dim3(64,8), b256, 0, stream>>>(W8, x, UTh, UTm, UTl);
  k_colnorm<<<dim3(64),   b256, 0, stream>>>(W8, W, Sv);           // Sv = S
  k_kv     <<<dim3(1024), b256, 0, stream>>>(KVTh, KVTl, W, Sv, scal+2);

  // ---- quantize factors + residual ----
  k_amax4<<<dim3(1024), b256, 0, stream>>>((const float4*)Ub, 131072, scal+1);
  k_qu   <<<dim3(2048), b256, 0, stream>>>(Aq, Ub, scal+1);
  k_qv   <<<dim3(64),   b256, 0, stream>>>(Vq, W, Sv, scal+2);
  k_res  <<<dim3(128,32), b256, 0, stream>>>(x, Uh, Ul, KVTh, KVTl, scal+3, Aq, 0);
  k_res  <<<dim3(128,32), b256, 0, stream>>>(x, Uh, Ul, KVTh, KVTl, scal+3, Aq, 1);

  // ---- low-rank fold + main GEMM ----
  k_m1  <<<dim3(64,8), b256, 0, stream>>>(M1, Vq, Bq);
  k_m2t <<<dim3(1024), b256, 0, stream>>>(Bq, M1, Sv, scal);
  k_gemm<<<dim3(16,32), dim3(512), 0, stream>>>(out, Aq, Bq, bias, scal);
}

// Round 4
// 1491.539 us; speedup vs baseline: 1.1362x; 1.1362x over previous
//
#include <hip/hip_runtime.h>
#include <stdint.h>

#define EPSF 1e-8f
#define KT 4160

typedef float  f32x4  __attribute__((ext_vector_type(4)));
typedef __bf16 bf16x8 __attribute__((ext_vector_type(8)));
typedef __bf16 bf16x4 __attribute__((ext_vector_type(4)));

// ---------------- workspace layout ----------------
// fp32 region (element offsets)
constexpr size_t oP    = 0;                     // P   [8192*64]
constexpr size_t oW    = oP  + 8192*64;         // W   [4096*64]
constexpr size_t oG    = oW  + 4096*64;         // Gram[64*64]
constexpr size_t oM1   = oG  + 64*64;           // M1  [64*4096]
constexpr size_t oScal = oM1 + 64*4096;         // 4 u32: amax_w, amax_u, amax_v, amax_r
constexpr size_t nZero1= oScal + 4;             // initial zero: P,W,G,M1,scal
constexpr size_t nZero2= oG + 64*64;            // iter-2 zero: P,W,G
constexpr size_t oS    = nZero1;                // 64
constexpr size_t oLinv = oS + 64;               // 64*64
constexpr size_t oV    = oLinv + 64*64;         // V  [4096*64]
constexpr size_t oU    = oV + 4096*64;          // Ub [8192*64]
constexpr size_t endF32= oU + 8192*64;
constexpr size_t bfByte= ((endF32*4 + 255)/256)*256;
// bf16 region (element offsets)
constexpr size_t oVq   = 0;                     // Vq [64*4096]
constexpr size_t oA    = oVq + 64*4096;         // A = [Rq | Uq]  [8192*4160]
constexpr size_t oB    = oA + (size_t)8192*4160;// B = [Wq | M2T] [4096*4160]
constexpr size_t oVcT  = oB + (size_t)4096*4160;// VcT h/m/l 3x[64*4096]
constexpr size_t oUT   = oVcT + 3*(size_t)64*4096;   // UT h/m/l 3x[64*8192]
constexpr size_t oUhl  = oUT + 3*(size_t)64*8192;    // U h/l 2x[8192*64]
constexpr size_t oKVT  = oUhl + 2*(size_t)8192*64;   // KVT h/l 2x[4096*64]
constexpr size_t endBF = oKVT + 2*(size_t)4096*64;
constexpr size_t WS_NEED = bfByte + endBF*2;

// ---------------- fp4 e2m1 helpers ----------------
__device__ __forceinline__ float qlevel(float a){
  if (a <= 0.25f) return 0.0f;
  if (a <= 0.75f) return 0.5f;
  if (a <= 1.25f) return 1.0f;
  if (a <= 1.75f) return 1.5f;
  if (a <= 2.5f)  return 2.0f;
  if (a <= 3.5f)  return 3.0f;
  if (a <= 5.0f)  return 4.0f;
  return 6.0f;
}
__device__ __forceinline__ float qgrid(float v, float s){
  float y = v / s;
  float l = qlevel(fabsf(y));
  return y < 0.0f ? -l : l;
}

// ---------------- utility ----------------
__global__ void k_zero(float* p, int n){
  for (int i = blockIdx.x*blockDim.x + threadIdx.x; i < n; i += gridDim.x*blockDim.x)
    p[i] = 0.0f;
}

__global__ void k_amax4(const float4* __restrict__ x, int n4, unsigned* __restrict__ out){
  float m = 0.f;
  for (int i = blockIdx.x*blockDim.x + threadIdx.x; i < n4; i += gridDim.x*blockDim.x){
    float4 v = x[i];
    m = fmaxf(m, fmaxf(fmaxf(fabsf(v.x), fabsf(v.y)), fmaxf(fabsf(v.z), fabsf(v.w))));
  }
  for (int o = 32; o > 0; o >>= 1) m = fmaxf(m, __shfl_down(m, o, 64));
  __shared__ float sm[4];
  int lane = threadIdx.x & 63, w = threadIdx.x >> 6;
  if (lane == 0) sm[w] = m;
  __syncthreads();
  if (threadIdx.x == 0)
    atomicMax(out, __float_as_uint(fmaxf(fmaxf(sm[0],sm[1]), fmaxf(sm[2],sm[3]))));
}

// ---------------- P += x @ Vc  via 3-word-split bf16 MFMA  grid(64,8) ----------------
// A-frags register-assembled from fp32 x; B = VcT h/m/l [64,4096] bf16.
__global__ __launch_bounds__(256) void k_gv(
    float* __restrict__ P, const float* __restrict__ x,
    const __bf16* __restrict__ Bh, const __bf16* __restrict__ Bm, const __bf16* __restrict__ Bl){
  int m0 = blockIdx.x * 128;
  int d0 = blockIdx.y * 512;
  int lane = threadIdx.x & 63, wave = threadIdx.x >> 6;
  int kgrp = lane >> 4, lrow = lane & 15;
  f32x4 acc[2][4] = {};
  for (int dc = d0; dc < d0 + 512; dc += 32){
    bf16x8 ah[2], am[2], al[2];
    #pragma unroll
    for (int f = 0; f < 2; f++){
      const float* g = x + (size_t)(m0 + wave*32 + f*16 + lrow)*4096 + dc + kgrp*8;
      float4 a = *(const float4*)g;
      float4 b = *(const float4*)(g + 4);
      float v[8] = {a.x,a.y,a.z,a.w,b.x,b.y,b.z,b.w};
      #pragma unroll
      for (int j = 0; j < 8; j++){
        __bf16 h = (__bf16)v[j];
        float r1 = v[j] - (float)h;
        __bf16 md = (__bf16)r1;
        float r2 = r1 - (float)md;
        ah[f][j] = h; am[f][j] = md; al[f][j] = (__bf16)r2;
      }
    }
    #pragma unroll
    for (int n = 0; n < 4; n++){
      size_t bo = (size_t)(n*16 + lrow)*4096 + dc + kgrp*8;
      bf16x8 bh = *(const bf16x8*)(Bh + bo);
      bf16x8 bm = *(const bf16x8*)(Bm + bo);
      bf16x8 bl = *(const bf16x8*)(Bl + bo);
      #pragma unroll
      for (int f = 0; f < 2; f++){
        acc[f][n] = __builtin_amdgcn_mfma_f32_16x16x32_bf16(ah[f], bh, acc[f][n],0,0,0);
        acc[f][n] = __builtin_amdgcn_mfma_f32_16x16x32_bf16(ah[f], bm, acc[f][n],0,0,0);
        acc[f][n] = __builtin_amdgcn_mfma_f32_16x16x32_bf16(am[f], bh, acc[f][n],0,0,0);
        acc[f][n] = __builtin_amdgcn_mfma_f32_16x16x32_bf16(ah[f], bl, acc[f][n],0,0,0);
        acc[f][n] = __builtin_amdgcn_mfma_f32_16x16x32_bf16(al[f], bh, acc[f][n],0,0,0);
        acc[f][n] = __builtin_amdgcn_mfma_f32_16x16x32_bf16(am[f], bm, acc[f][n],0,0,0);
      }
    }
  }
  #pragma unroll
  for (int f = 0; f < 2; f++)
    #pragma unroll
    for (int n = 0; n < 4; n++)
      #pragma unroll
      for (int r = 0; r < 4; r++)
        atomicAdd(&P[(size_t)(m0 + wave*32 + f*16 + kgrp*4 + r)*64 + n*16 + lrow], acc[f][n][r]);
}

// ---------------- W += x^T @ U  (transposed A from fp32 x)  grid(64,8) ----------------
__global__ __launch_bounds__(256) void k_gtu(
    float* __restrict__ W, const float* __restrict__ x,
    const __bf16* __restrict__ Bh, const __bf16* __restrict__ Bm, const __bf16* __restrict__ Bl){
  int d0 = blockIdx.x * 64;
  int m0 = blockIdx.y * 1024;
  int lane = threadIdx.x & 63, wave = threadIdx.x >> 6;
  int kgrp = lane >> 4, lrow = lane & 15;
  int dcol = d0 + wave*16 + lrow;
  f32x4 acc[4] = {};
  for (int mc = m0; mc < m0 + 1024; mc += 32){
    bf16x8 ah, am, al;
    int mb = mc + kgrp*8;
    #pragma unroll
    for (int j = 0; j < 8; j++){
      float v = x[(size_t)(mb + j)*4096 + dcol];
      __bf16 h = (__bf16)v;
      float r1 = v - (float)h;
      __bf16 md = (__bf16)r1;
      float r2 = r1 - (float)md;
      ah[j] = h; am[j] = md; al[j] = (__bf16)r2;
    }
    #pragma unroll
    for (int n = 0; n < 4; n++){
      size_t bo = (size_t)(n*16 + lrow)*8192 + mc + kgrp*8;
      bf16x8 bh = *(const bf16x8*)(Bh + bo);
      bf16x8 bm = *(const bf16x8*)(Bm + bo);
      bf16x8 bl = *(const bf16x8*)(Bl + bo);
      acc[n] = __builtin_amdgcn_mfma_f32_16x16x32_bf16(ah, bh, acc[n],0,0,0);
      acc[n] = __builtin_amdgcn_mfma_f32_16x16x32_bf16(ah, bm, acc[n],0,0,0);
      acc[n] = __builtin_amdgcn_mfma_f32_16x16x32_bf16(am, bh, acc[n],0,0,0);
      acc[n] = __builtin_amdgcn_mfma_f32_16x16x32_bf16(ah, bl, acc[n],0,0,0);
      acc[n] = __builtin_amdgcn_mfma_f32_16x16x32_bf16(al, bh, acc[n],0,0,0);
      acc[n] = __builtin_amdgcn_mfma_f32_16x16x32_bf16(am, bm, acc[n],0,0,0);
    }
  }
  #pragma unroll
  for (int n = 0; n < 4; n++)
    #pragma unroll
    for (int r = 0; r < 4; r++)
      atomicAdd(&W[(size_t)(d0 + wave*16 + kgrp*4 + r)*64 + n*16 + lrow], acc[n][r]);
}

// ---------------- Gram += Pchunk^T Pchunk   grid 64 ----------------
__global__ void k_gram(const float* __restrict__ P, float* __restrict__ Gram){
  __shared__ float Pt[128][65];
  int m0 = blockIdx.x * 128;
  int t = threadIdx.x;
  for (int i = 0; i < 32; i++){
    int idx = i*256 + t; int r = idx >> 6, c = idx & 63;
    Pt[r][c] = P[(size_t)(m0+r)*64 + c];
  }
  __syncthreads();
  int ti = t >> 4, tj = t & 15;
  float acc[4][4] = {};
  for (int r = 0; r < 128; r++){
    float a[4], b[4];
    #pragma unroll
    for (int q = 0; q < 4; q++) a[q] = Pt[r][ti*4+q];
    #pragma unroll
    for (int q = 0; q < 4; q++) b[q] = Pt[r][tj*4+q];
    #pragma unroll
    for (int xx = 0; xx < 4; xx++)
      #pragma unroll
      for (int y = 0; y < 4; y++) acc[xx][y] += a[xx]*b[y];
  }
  for (int xx = 0; xx < 4; xx++)
    for (int y = 0; y < 4; y++)
      atomicAdd(&Gram[(ti*4+xx)*64 + tj*4+y], acc[xx][y]);
}

// ---------------- fp64 Cholesky of Gram + lower-tri inverse ----------------
__global__ void k_cholinv(const float* __restrict__ Gram, float* __restrict__ Linv){
  __shared__ double A[64][64];
  __shared__ double Li[64][64];
  int t = threadIdx.x;
  for (int j = 0; j < 64; j++){ A[t][j] = (double)Gram[t*64+j]; Li[t][j] = 0.0; }
  __syncthreads();
  for (int k = 0; k < 64; k++){
    if (t == k) A[k][k] = sqrt(A[k][k]);
    __syncthreads();
    if (t > k) A[t][k] /= A[k][k];
    __syncthreads();
    if (t > k){
      double aik = A[t][k];
      for (int j = k+1; j <= t; j++) A[t][j] -= aik * A[j][k];
    }
    __syncthreads();
  }
  for (int i = t; i < 64; i++){
    double s = (i == t) ? 1.0 : 0.0;
    for (int p = t; p < i; p++) s -= A[i][p] * Li[p][t];
    Li[i][t] = s / A[i][i];
  }
  __syncthreads();
  for (int j = 0; j < 64; j++) Linv[t*64+j] = (float)Li[t][j];
}

// ---------------- U = P @ Linv^T   grid 128 ----------------
__global__ void k_applyq(float* __restrict__ U, const float* __restrict__ P,
                         const float* __restrict__ Linv){
  __shared__ float Pt[64][65];
  __shared__ float Lt[64][65];
  int m0 = blockIdx.x * 64;
  int t = threadIdx.x;
  for (int i = 0; i < 16; i++){
    int idx = i*256 + t; int r = idx >> 6, c = idx & 63;
    Pt[r][c] = P[(size_t)(m0+r)*64 + c];
    Lt[r][c] = Linv[r*64 + c];
  }
  __syncthreads();
  int tm = t >> 4, tj = t & 15;
  float acc[4][4] = {};
  for (int i = 0; i < 64; i++){
    float p[4], lv[4];
    #pragma unroll
    for (int a = 0; a < 4; a++) p[a]  = Pt[tm*4+a][i];
    #pragma unroll
    for (int b = 0; b < 4; b++) lv[b] = Lt[tj*4+b][i];
    #pragma unroll
    for (int a = 0; a < 4; a++)
      #pragma unroll
      for (int b = 0; b < 4; b++) acc[a][b] += p[a]*lv[b];
  }
  for (int a = 0; a < 4; a++)
    for (int b = 0; b < 4; b++)
      U[(size_t)(m0+tm*4+a)*64 + tj*4+b] = acc[a][b];
}

// ---------------- column norms of W[4096,64]  grid 64 ----------------
__global__ void k_colnorm(const float* __restrict__ W, float* __restrict__ cn){
  int k = blockIdx.x;
  float s = 0.f;
  for (int d = threadIdx.x; d < 4096; d += 256){
    float v = W[(size_t)d*64 + k];
    s += v*v;
  }
  for (int o = 32; o > 0; o >>= 1) s += __shfl_down(s, o, 64);
  __shared__ float sm[4];
  int lane = threadIdx.x & 63, w = threadIdx.x >> 6;
  if (lane == 0) sm[w] = s;
  __syncthreads();
  if (threadIdx.x == 0) cn[k] = sqrtf(sm[0]+sm[1]+sm[2]+sm[3]);
}

__global__ void k_vnorm(float* __restrict__ V, const float* __restrict__ W,
                        const float* __restrict__ cn){
  int i = blockIdx.x*256 + threadIdx.x;
  int k = i & 63;
  V[i] = W[i] / (cn[k] + EPSF);
}

// Vn = W/(S+EPS); KVT[d][k] = S*Vn (bf16 h/l); amax_v   grid 1024
__global__ void k_vnkv(float* __restrict__ V, __bf16* __restrict__ Kh, __bf16* __restrict__ Kl,
                       const float* __restrict__ W, const float* __restrict__ S,
                       unsigned* __restrict__ amaxv){
  int i = blockIdx.x*256 + threadIdx.x;
  int k = i & 63, d = i >> 6;
  float s = S[k];
  float vn = W[i] / (s + EPSF);
  V[i] = vn;
  float kv = s * vn;
  __bf16 h = (__bf16)kv;
  Kh[(size_t)d*64 + k] = h;
  Kl[(size_t)d*64 + k] = (__bf16)(kv - (float)h);
  float m = fabsf(vn);
  for (int o = 32; o > 0; o >>= 1) m = fmaxf(m, __shfl_down(m, o, 64));
  __shared__ float sm[4];
  int lane = threadIdx.x & 63, w = threadIdx.x >> 6;
  if (lane == 0) sm[w] = m;
  __syncthreads();
  if (threadIdx.x == 0)
    atomicMax(amaxv, __float_as_uint(fmaxf(fmaxf(sm[0],sm[1]), fmaxf(sm[2],sm[3]))));
}

// ---------------- transpose+3-split prep: Vc[4096,64] -> VcT h/m/l [64,4096]  grid 64 ----------------
__global__ void k_prep_vct(const float* __restrict__ Vc, __bf16* __restrict__ Th,
                           __bf16* __restrict__ Tm, __bf16* __restrict__ Tl){
  __shared__ float Vt[64][65];
  int d0 = blockIdx.x * 64;
  int t = threadIdx.x;
  for (int i = 0; i < 16; i++){
    int idx = i*256 + t; int r = idx >> 6, c = idx & 63;
    Vt[r][c] = Vc[(size_t)(d0 + r)*64 + c];
  }
  __syncthreads();
  for (int i = 0; i < 16; i++){
    int idx = i*256 + t; int k = idx >> 6, dd = idx & 63;
    float v = Vt[dd][k];
    __bf16 h = (__bf16)v;
    float r1 = v - (float)h;
    __bf16 md = (__bf16)r1;
    float r2 = r1 - (float)md;
    size_t o = (size_t)k*4096 + d0 + dd;
    Th[o] = h; Tm[o] = md; Tl[o] = (__bf16)r2;
  }
}

// prep U: Ub[8192,64] -> U h/l [8192,64] + UT h/m/l [64,8192]   grid 128
__global__ void k_prep_u(const float* __restrict__ Ub, __bf16* __restrict__ Uh, __bf16* __restrict__ Ul,
                         __bf16* __restrict__ Th, __bf16* __restrict__ Tm, __bf16* __restrict__ Tl){
  __shared__ float Ut[64][65];
  int m0 = blockIdx.x * 64;
  int t = threadIdx.x;
  for (int i = 0; i < 16; i++){
    int idx = i*256 + t; int r = idx >> 6, c = idx & 63;
    float v = Ub[(size_t)(m0 + r)*64 + c];
    Ut[r][c] = v;
    __bf16 h = (__bf16)v;
    Uh[(size_t)(m0+r)*64 + c] = h;
    Ul[(size_t)(m0+r)*64 + c] = (__bf16)(v - (float)h);
  }
  __syncthreads();
  for (int i = 0; i < 16; i++){
    int idx = i*256 + t; int k = idx >> 6, mm = idx & 63;
    float v = Ut[mm][k];
    __bf16 h = (__bf16)v;
    float r1 = v - (float)h;
    __bf16 md = (__bf16)r1;
    float r2 = r1 - (float)md;
    size_t o = (size_t)k*8192 + m0 + mm;
    Th[o] = h; Tm[o] = md; Tl[o] = (__bf16)r2;
  }
}

// ---------------- quantize weight -> Bq[:, :4096]  (float4)  grid 16384 ----------------
__global__ void k_qw(__bf16* __restrict__ Bq, const float* __restrict__ w,
                     const unsigned* __restrict__ amaxw){
  float s = fmaxf(__uint_as_float(*amaxw) / 6.0f, EPSF);
  int i = blockIdx.x*256 + threadIdx.x;          // 4.19M groups of 4
  int n = i >> 10, d = (i & 1023)*4;
  float4 v = *(const float4*)(w + (size_t)n*4096 + d);
  bf16x4 o;
  o[0] = (__bf16)qgrid(v.x, s); o[1] = (__bf16)qgrid(v.y, s);
  o[2] = (__bf16)qgrid(v.z, s); o[3] = (__bf16)qgrid(v.w, s);
  *(bf16x4*)(Bq + (size_t)n*4160 + d) = o;
}

// ---------------- quantize U -> Aq[:, 4096:4160]  grid 2048 ----------------
__global__ void k_qu(__bf16* __restrict__ Aq, const float* __restrict__ U,
                     const unsigned* __restrict__ amaxu){
  float s = fmaxf(__uint_as_float(*amaxu) / 6.0f, EPSF);
  int i = blockIdx.x*256 + threadIdx.x;
  int m = i >> 6, k = i & 63;
  Aq[(size_t)m*4160 + 4096 + k] = (__bf16)qgrid(U[i], s);
}

// ---------------- quantize V -> Vq[k][d] (LDS transpose)  grid 64 ----------------
__global__ void k_qv(__bf16* __restrict__ Vq, const float* __restrict__ V,
                     const unsigned* __restrict__ amaxv){
  __shared__ float Vt[64][65];
  float s = fmaxf(__uint_as_float(*amaxv)/6.0f, EPSF);
  int d0 = blockIdx.x * 64;
  int t = threadIdx.x;
  for (int i = 0; i < 16; i++){
    int idx = i*256 + t; int r = idx >> 6, c = idx & 63;
    Vt[r][c] = V[(size_t)(d0 + r)*64 + c];
  }
  __syncthreads();
  for (int i = 0; i < 16; i++){
    int idx = i*256 + t; int k = idx >> 6, dd = idx & 63;
    Vq[(size_t)k*4096 + d0 + dd] = (__bf16)qgrid(Vt[dd][k], s);
  }
}

// ---------------- residual: ker = U@KV via 2-split MFMA; amax or quantize  grid(128,32) ----------------
__global__ __launch_bounds__(256) void k_res(
    const float* __restrict__ x, const __bf16* __restrict__ Uh, const __bf16* __restrict__ Ul,
    const __bf16* __restrict__ Kh, const __bf16* __restrict__ Kl,
    unsigned* __restrict__ amaxr, __bf16* __restrict__ Aq, int mode){
  int m0 = blockIdx.x * 64, n0 = blockIdx.y * 128;
  int lane = threadIdx.x & 63, wave = threadIdx.x >> 6;
  int kgrp = lane >> 4, lrow = lane & 15;
  int mrow = m0 + wave*16 + lrow;
  f32x4 acc[8] = {};
  #pragma unroll
  for (int ks = 0; ks < 2; ks++){
    size_t ao = (size_t)mrow*64 + ks*32 + kgrp*8;
    bf16x8 uh = *(const bf16x8*)(Uh + ao);
    bf16x8 ul = *(const bf16x8*)(Ul + ao);
    #pragma unroll
    for (int n = 0; n < 8; n++){
      size_t bo = (size_t)(n0 + n*16 + lrow)*64 + ks*32 + kgrp*8;
      bf16x8 kh = *(const bf16x8*)(Kh + bo);
      bf16x8 kl = *(const bf16x8*)(Kl + bo);
      acc[n] = __builtin_amdgcn_mfma_f32_16x16x32_bf16(uh, kh, acc[n],0,0,0);
      acc[n] = __builtin_amdgcn_mfma_f32_16x16x32_bf16(uh, kl, acc[n],0,0,0);
      acc[n] = __builtin_amdgcn_mfma_f32_16x16x32_bf16(ul, kh, acc[n],0,0,0);
    }
  }
  int mb = m0 + wave*16 + kgrp*4;
  if (mode == 0){
    float mx = 0.f;
    #pragma unroll
    for (int n = 0; n < 8; n++){
      int c = n0 + n*16 + lrow;
      #pragma unroll
      for (int r = 0; r < 4; r++)
        mx = fmaxf(mx, fabsf(x[(size_t)(mb + r)*4096 + c] - acc[n][r]));
    }
    for (int o = 32; o > 0; o >>= 1) mx = fmaxf(mx, __shfl_down(mx, o, 64));
    __shared__ float sm[4];
    if (lane == 0) sm[wave] = mx;
    __syncthreads();
    if (threadIdx.x == 0)
      atomicMax(amaxr, __float_as_uint(fmaxf(fmaxf(sm[0],sm[1]), fmaxf(sm[2],sm[3]))));
  } else {
    float s = fmaxf(__uint_as_float(*amaxr)/6.0f, EPSF);
    #pragma unroll
    for (int n = 0; n < 8; n++){
      int c = n0 + n*16 + lrow;
      #pragma unroll
      for (int r = 0; r < 4; r++)
        Aq[(size_t)(mb + r)*4160 + c] =
          (__bf16)qgrid(x[(size_t)(mb + r)*4096 + c] - acc[n][r], s);
    }
  }
}

// ---------------- M1 += Vq @ Wq^T  (exact bf16 MFMA)  grid(64,8) ----------------
__global__ __launch_bounds__(256) void k_m1(
    float* __restrict__ M1g, const __bf16* __restrict__ Vq, const __bf16* __restrict__ Bq){
  int n0 = blockIdx.x * 64;
  int k0 = blockIdx.y * 512;
  int lane = threadIdx.x & 63, wave = threadIdx.x >> 6;
  int kgrp = lane >> 4, lrow = lane & 15;
  int nrow = n0 + wave*16 + lrow;
  f32x4 acc[4] = {};
  for (int kc = k0; kc < k0 + 512; kc += 32){
    bf16x8 fb = *(const bf16x8*)(Bq + (size_t)nrow*4160 + kc + kgrp*8);
    #pragma unroll
    for (int mt = 0; mt < 4; mt++){
      bf16x8 fa = *(const bf16x8*)(Vq + (size_t)(mt*16 + lrow)*4096 + kc + kgrp*8);
      acc[mt] = __builtin_amdgcn_mfma_f32_16x16x32_bf16(fa, fb, acc[mt],0,0,0);
    }
  }
  #pragma unroll
  for (int mt = 0; mt < 4; mt++)
    #pragma unroll
    for (int r = 0; r < 4; r++)
      atomicAdd(&M1g[(size_t)(mt*16 + kgrp*4 + r)*4096 + nrow], acc[mt][r]);
}

// ---------------- M2T: Bq[:, 4096:4160] = M1[k][n] * su*sv*S[k]/sr  grid 1024 ----------------
__global__ void k_m2t(__bf16* __restrict__ Bq, const float* __restrict__ M1g,
                      const float* __restrict__ S, const unsigned* __restrict__ scal){
  float su = fmaxf(__uint_as_float(scal[1])/6.0f, EPSF);
  float sv = fmaxf(__uint_as_float(scal[2])/6.0f, EPSF);
  float sr = fmaxf(__uint_as_float(scal[3])/6.0f, EPSF);
  int i = blockIdx.x*256 + threadIdx.x;
  int n = i >> 6, k = i & 63;
  float v = M1g[(size_t)k*4096 + n] * (su * sv * S[k] / sr);
  Bq[(size_t)n*4160 + 4096 + k] = (__bf16)v;
}

// ---------------- main bf16 MFMA GEMM: out = (A @ B^T)*sr*sw + bias ----------------
// 256x256 tile, BK=32, 512 threads (8 waves, 2Mx4N), 4-deep LDS ring (128 KiB).
// T3+T4: counted s_waitcnt vmcnt(8) (never drained to 0 in steady state) + builtin
// s_barrier (does NOT drain vmcnt), T5 setprio around the 32-MFMA cluster.
// R3 post-mortem: default (bx,by)->(n0,m0) mapping is the best known (XCD remap
// DOUBLED fetch); kernel is fetch-path-bound (dur == hbm_bytes/1.86 TB/s).
// R4 change: NONTEMPORAL epilogue stores — out is write-only; write-allocate was
// evicting the A/B panels from L3 during the GEMM (FETCH 300 MB ~ 3x A+B).
__global__ __launch_bounds__(512, 2)
void k_gemm(float* __restrict__ out, const __bf16* __restrict__ A,
            const __bf16* __restrict__ B, const float* __restrict__ bias,
            const unsigned* __restrict__ scal){
  __shared__ __align__(16) __bf16 As[4*8192];   // 4 ring slots x 128 packed rows x 64 el
  __shared__ __align__(16) __bf16 Bs[4*8192];
  const int m0 = blockIdx.y * 256, n0 = blockIdx.x * 256;
  const int tid = threadIdx.x;
  const int lane = tid & 63, wave = tid >> 6;
  const int wrow = wave >> 2, wcol = wave & 3;     // 2 x 4 wave grid
  const int kg = lane >> 4, lr = lane & 15;
  f32x4 acc[8][4] = {};

  auto STAGE = [&](int tt){
    __bf16* as = &As[(tt & 3) * 8192];
    __bf16* bs = &Bs[(tt & 3) * 8192];
    const int kt = tt * 32;
    #pragma unroll
    for (int q = 0; q < 2; q++){
      int idx = q * 512 + tid;                 // 1024 16B-slots per matrix
      int rp  = idx >> 3;                      // packed LDS row 0..127
      int sp  = (idx & 7) ^ (rp & 7);          // unswizzled slot
      int grow = rp * 2 + (sp >> 2);           // global tile row 0..255
      int gcol = (sp & 3) * 8;                 // global k element 0..24
      const __bf16* ga = A + (size_t)(m0 + grow) * KT + kt + gcol;
      const __bf16* gb = B + (size_t)(n0 + grow) * KT + kt + gcol;
      __bf16* la = as + (size_t)(idx & ~63) * 8;
      __bf16* lb = bs + (size_t)(idx & ~63) * 8;
      __builtin_amdgcn_global_load_lds((const __attribute__((address_space(1))) uint32_t*)ga,
                                       (__attribute__((address_space(3))) uint32_t*)la, 16, 0, 0);
      __builtin_amdgcn_global_load_lds((const __attribute__((address_space(1))) uint32_t*)gb,
                                       (__attribute__((address_space(3))) uint32_t*)lb, 16, 0, 0);
    }
  };

  auto BODY = [&](int t, bool stage){
    const __bf16* as = &As[(t & 3) * 8192];
    const __bf16* bs = &Bs[(t & 3) * 8192];
    bf16x8 fa[8], fb[4];
    #pragma unroll
    for (int mf = 0; mf < 8; mf++){
      int row = wrow*128 + mf*16 + lr;
      int rp  = row >> 1;
      int sl  = (((row & 1) << 2) | kg) ^ (rp & 7);
      fa[mf] = *(const bf16x8*)(as + (size_t)rp*64 + sl*8);
    }
    #pragma unroll
    for (int nf = 0; nf < 4; nf++){
      int row = wcol*64 + nf*16 + lr;
      int rp  = row >> 1;
      int sl  = (((row & 1) << 2) | kg) ^ (rp & 7);
      fb[nf] = *(const bf16x8*)(bs + (size_t)rp*64 + sl*8);
    }
    if (stage) STAGE(t + 3);                    // slot (t+3)&3: last read at iter t-1, safe
    __builtin_amdgcn_s_setprio(1);
    #pragma unroll
    for (int mf = 0; mf < 8; mf++)
      #pragma unroll
      for (int nf = 0; nf < 4; nf++)
        acc[mf][nf] = __builtin_amdgcn_mfma_f32_16x16x32_bf16(fa[mf], fb[nf], acc[mf][nf], 0, 0, 0);
    __builtin_amdgcn_s_setprio(0);
  };

  STAGE(0); STAGE(1); STAGE(2);                // prologue: 3 tiles (12 loads) in flight

  const int NT = KT / 32;                      // 130
  for (int t = 0; t < NT - 2; t++){
    asm volatile("s_waitcnt vmcnt(8)" ::: "memory");
    __builtin_amdgcn_s_barrier();
    BODY(t, t < NT - 3);
  }
  asm volatile("s_waitcnt vmcnt(4)" ::: "memory");
  __builtin_amdgcn_s_barrier();
  BODY(NT - 2, false);
  asm volatile("s_waitcnt vmcnt(0)" ::: "memory");
  __builtin_amdgcn_s_barrier();
  BODY(NT - 1, false);

  float sr = fmaxf(__uint_as_float(scal[3])/6.0f, EPSF);
  float sw = fmaxf(__uint_as_float(scal[0])/6.0f, EPSF);
  float srw = sr * sw;
  #pragma unroll
  for (int nf = 0; nf < 4; nf++){
    int n = n0 + wcol*64 + nf*16 + lr;
    float bv = bias[n];
    #pragma unroll
    for (int mf = 0; mf < 8; mf++){
      int mb = m0 + wrow*128 + mf*16 + 4*kg;
      #pragma unroll
      for (int r = 0; r < 4; r++)
        __builtin_nontemporal_store(acc[mf][nf][r]*srw + bv,
                                    &out[(size_t)(mb + r)*4096 + n]);
    }
  }
}

// ---------------- host side ----------------
extern "C" void kernel_launch(void* const* d_in, const int* in_sizes, int n_in,
                              void* d_out, int out_size, void* d_ws, size_t ws_size,
                              hipStream_t stream){
  const float* x    = (const float*)d_in[0];   // [8192, 4096]
  const float* wt   = (const float*)d_in[1];   // [4096, 4096]
  const float* bias = (const float*)d_in[2];   // [4096]
  const float* V0   = (const float*)d_in[3];   // [4096, 64]
  float* out = (float*)d_out;
  if (ws_size < WS_NEED) return;

  float* F = (float*)d_ws;
  unsigned* scal = (unsigned*)(F + oScal);
  __bf16* BFp = (__bf16*)((char*)d_ws + bfByte);
  __bf16* Vq  = BFp + oVq;
  __bf16* Aq  = BFp + oA;
  __bf16* Bq  = BFp + oB;
  __bf16* VcTh = BFp + oVcT,              *VcTm = VcTh + (size_t)64*4096, *VcTl = VcTm + (size_t)64*4096;
  __bf16* UTh  = BFp + oUT,               *UTm  = UTh + (size_t)64*8192,  *UTl  = UTm + (size_t)64*8192;
  __bf16* Uh   = BFp + oUhl,              *Ul   = Uh + (size_t)8192*64;
  __bf16* KVTh = BFp + oKVT,              *KVTl = KVTh + (size_t)4096*64;
  float *P = F+oP, *W = F+oW, *Gm = F+oG, *M1 = F+oM1, *Sv = F+oS,
        *Li = F+oLinv, *V = F+oV, *Ub = F+oU;

  dim3 b256(256);
  k_zero <<<dim3(2048), b256, 0, stream>>>(F, (int)nZero1);
  k_amax4<<<dim3(1024), b256, 0, stream>>>((const float4*)wt, 4194304, scal+0);
  k_qw   <<<dim3(16384), b256, 0, stream>>>(Bq, wt, scal+0);

  // ---- power iteration 1 ----
  k_prep_vct<<<dim3(64),  b256, 0, stream>>>(V0, VcTh, VcTm, VcTl);
  k_gv     <<<dim3(64,8), b256, 0, stream>>>(P, x, VcTh, VcTm, VcTl);
  k_gram   <<<dim3(64),   b256, 0, stream>>>(P, Gm);
  k_cholinv<<<dim3(1), dim3(64), 0, stream>>>(Gm, Li);
  k_applyq <<<dim3(128),  b256, 0, stream>>>(Ub, P, Li);
  k_prep_u <<<dim3(128),  b256, 0, stream>>>(Ub, Uh, Ul, UTh, UTm, UTl);
  k_gtu    <<<dim3(64,8), b256, 0, stream>>>(W, x, UTh, UTm, UTl);
  k_colnorm<<<dim3(64),   b256, 0, stream>>>(W, Sv);
  k_vnorm  <<<dim3(1024), b256, 0, stream>>>(V, W, Sv);

  // ---- power iteration 2 ----
  k_prep_vct<<<dim3(64),  b256, 0, stream>>>(V, VcTh, VcTm, VcTl);
  k_zero   <<<dim3(2048), b256, 0, stream>>>(F, (int)nZero2);      // P, W, Gram
  k_gv     <<<dim3(64,8), b256, 0, stream>>>(P, x, VcTh, VcTm, VcTl);
  k_gram   <<<dim3(64),   b256, 0, stream>>>(P, Gm);
  k_cholinv<<<dim3(1), dim3(64), 0, stream>>>(Gm, Li);
  k_applyq <<<dim3(128),  b256, 0, stream>>>(Ub, P, Li);
  k_prep_u <<<dim3(128),  b256, 0, stream>>>(Ub, Uh, Ul, UTh, UTm, UTl);
  k_gtu    <<<dim3(64,8), b256, 0, stream>>>(W, x, UTh, UTm, UTl);
  k_colnorm<<<dim3(64),   b256, 0, stream>>>(W, Sv);               // Sv = S
  k_vnkv   <<<dim3(1024), b256, 0, stream>>>(V, KVTh, KVTl, W, Sv, scal+2);

  // ---- quantize factors + residual ----
  k_amax4<<<dim3(1024), b256, 0, stream>>>((const float4*)Ub, 131072, scal+1);
  k_qu   <<<dim3(2048), b256, 0, stream>>>(Aq, Ub, scal+1);
  k_qv   <<<dim3(64),   b256, 0, stream>>>(Vq, V, scal+2);
  k_res  <<<dim3(128,32), b256, 0, stream>>>(x, Uh, Ul, KVTh, KVTl, scal+3, Aq, 0);
  k_res  <<<dim3(128,32), b256, 0, stream>>>(x, Uh, Ul, KVTh, KVTl, scal+3, Aq, 1);

  // ---- low-rank fold + main GEMM ----
  k_m1  <<<dim3(64,8), b256, 0, stream>>>(M1, Vq, Bq);
  k_m2t <<<dim3(1024), b256, 0, stream>>>(Bq, M1, Sv, scal);
  k_gemm<<<dim3(16,32), dim3(512), 0, stream>>>(out, Aq, Bq, bias, scal);
}

// Round 7
// 1452.814 us; speedup vs baseline: 1.1664x; 1.0267x over previous
//
#include <hip/hip_runtime.h>
#include <stdint.h>

#define EPSF 1e-8f
#define KT 4160

typedef float  f32x4  __attribute__((ext_vector_type(4)));
typedef __bf16 bf16x8 __attribute__((ext_vector_type(8)));
typedef __bf16 bf16x4 __attribute__((ext_vector_type(4)));

// ---------------- workspace layout ----------------
// fp32 region (element offsets)
constexpr size_t oP    = 0;                     // P   [8192*64]
constexpr size_t oW    = oP  + 8192*64;         // W   [4096*64]
constexpr size_t oG    = oW  + 4096*64;         // Gram[64*64]
constexpr size_t oM1   = oG  + 64*64;           // M1  [64*4096]
constexpr size_t oScal = oM1 + 64*4096;         // 4 u32: amax_w, amax_u, amax_v, amax_r
constexpr size_t nZero1= oScal + 4;             // initial zero: P,W,G,M1,scal
constexpr size_t nZero2= oG + 64*64;            // iter-2 zero: P,W,G
constexpr size_t oS    = nZero1;                // 64
constexpr size_t oLinv = oS + 64;               // 64*64
constexpr size_t oV    = oLinv + 64*64;         // V  [4096*64]
constexpr size_t oU    = oV + 4096*64;          // Ub [8192*64]
constexpr size_t endF32= oU + 8192*64;
constexpr size_t bfByte= ((endF32*4 + 255)/256)*256;
// bf16 region (element offsets)
constexpr size_t oVq   = 0;                     // Vq [64*4096]
constexpr size_t oA    = oVq + 64*4096;         // A = [Rq | Uq]  [8192*4160]
constexpr size_t oB    = oA + (size_t)8192*4160;// B = [Wq | M2T] [4096*4160]
constexpr size_t oVcT  = oB + (size_t)4096*4160;// VcT h/m/l 3x[64*4096]
constexpr size_t oUT   = oVcT + 3*(size_t)64*4096;   // UT h/m/l 3x[64*8192]
constexpr size_t oUhl  = oUT + 3*(size_t)64*8192;    // U h/l 2x[8192*64]
constexpr size_t oKVT  = oUhl + 2*(size_t)8192*64;   // KVT h/l 2x[4096*64]
constexpr size_t endBF = oKVT + 2*(size_t)4096*64;
constexpr size_t WS_NEED = bfByte + endBF*2;

// ---------------- fp4 e2m1 helpers ----------------
__device__ __forceinline__ float qlevel(float a){
  if (a <= 0.25f) return 0.0f;
  if (a <= 0.75f) return 0.5f;
  if (a <= 1.25f) return 1.0f;
  if (a <= 1.75f) return 1.5f;
  if (a <= 2.5f)  return 2.0f;
  if (a <= 3.5f)  return 3.0f;
  if (a <= 5.0f)  return 4.0f;
  return 6.0f;
}
__device__ __forceinline__ float qgrid(float v, float s){
  float y = v / s;
  float l = qlevel(fabsf(y));
  return y < 0.0f ? -l : l;
}

// ---------------- utility ----------------
__global__ void k_zero(float* p, int n){
  for (int i = blockIdx.x*blockDim.x + threadIdx.x; i < n; i += gridDim.x*blockDim.x)
    p[i] = 0.0f;
}

__global__ void k_amax4(const float4* __restrict__ x, int n4, unsigned* __restrict__ out){
  float m = 0.f;
  for (int i = blockIdx.x*blockDim.x + threadIdx.x; i < n4; i += gridDim.x*blockDim.x){
    float4 v = x[i];
    m = fmaxf(m, fmaxf(fmaxf(fabsf(v.x), fabsf(v.y)), fmaxf(fabsf(v.z), fabsf(v.w))));
  }
  for (int o = 32; o > 0; o >>= 1) m = fmaxf(m, __shfl_down(m, o, 64));
  __shared__ float sm[4];
  int lane = threadIdx.x & 63, w = threadIdx.x >> 6;
  if (lane == 0) sm[w] = m;
  __syncthreads();
  if (threadIdx.x == 0)
    atomicMax(out, __float_as_uint(fmaxf(fmaxf(sm[0],sm[1]), fmaxf(sm[2],sm[3]))));
}

// ---------------- P += x @ Vc  via 3-word-split bf16 MFMA  grid(64,8) ----------------
// A-frags register-assembled from fp32 x; B = VcT h/m/l [64,4096] bf16.
__global__ __launch_bounds__(256) void k_gv(
    float* __restrict__ P, const float* __restrict__ x,
    const __bf16* __restrict__ Bh, const __bf16* __restrict__ Bm, const __bf16* __restrict__ Bl){
  int m0 = blockIdx.x * 128;
  int d0 = blockIdx.y * 512;
  int lane = threadIdx.x & 63, wave = threadIdx.x >> 6;
  int kgrp = lane >> 4, lrow = lane & 15;
  f32x4 acc[2][4] = {};
  for (int dc = d0; dc < d0 + 512; dc += 32){
    bf16x8 ah[2], am[2], al[2];
    #pragma unroll
    for (int f = 0; f < 2; f++){
      const float* g = x + (size_t)(m0 + wave*32 + f*16 + lrow)*4096 + dc + kgrp*8;
      float4 a = *(const float4*)g;
      float4 b = *(const float4*)(g + 4);
      float v[8] = {a.x,a.y,a.z,a.w,b.x,b.y,b.z,b.w};
      #pragma unroll
      for (int j = 0; j < 8; j++){
        __bf16 h = (__bf16)v[j];
        float r1 = v[j] - (float)h;
        __bf16 md = (__bf16)r1;
        float r2 = r1 - (float)md;
        ah[f][j] = h; am[f][j] = md; al[f][j] = (__bf16)r2;
      }
    }
    #pragma unroll
    for (int n = 0; n < 4; n++){
      size_t bo = (size_t)(n*16 + lrow)*4096 + dc + kgrp*8;
      bf16x8 bh = *(const bf16x8*)(Bh + bo);
      bf16x8 bm = *(const bf16x8*)(Bm + bo);
      bf16x8 bl = *(const bf16x8*)(Bl + bo);
      #pragma unroll
      for (int f = 0; f < 2; f++){
        acc[f][n] = __builtin_amdgcn_mfma_f32_16x16x32_bf16(ah[f], bh, acc[f][n],0,0,0);
        acc[f][n] = __builtin_amdgcn_mfma_f32_16x16x32_bf16(ah[f], bm, acc[f][n],0,0,0);
        acc[f][n] = __builtin_amdgcn_mfma_f32_16x16x32_bf16(am[f], bh, acc[f][n],0,0,0);
        acc[f][n] = __builtin_amdgcn_mfma_f32_16x16x32_bf16(ah[f], bl, acc[f][n],0,0,0);
        acc[f][n] = __builtin_amdgcn_mfma_f32_16x16x32_bf16(al[f], bh, acc[f][n],0,0,0);
        acc[f][n] = __builtin_amdgcn_mfma_f32_16x16x32_bf16(am[f], bm, acc[f][n],0,0,0);
      }
    }
  }
  #pragma unroll
  for (int f = 0; f < 2; f++)
    #pragma unroll
    for (int n = 0; n < 4; n++)
      #pragma unroll
      for (int r = 0; r < 4; r++)
        atomicAdd(&P[(size_t)(m0 + wave*32 + f*16 + kgrp*4 + r)*64 + n*16 + lrow], acc[f][n][r]);
}

// ---------------- W += x^T @ U  (LDS-transposed x, coalesced loads)  grid(64,8) ----------------
// Replaces per-lane scalar transposed reads of x (64B segments, latency-bound)
// with a shared 64x64 LDS tile loaded via coalesced float4 row reads. Same 3-split,
// same mc order, same MFMA sequence -> bitwise-identical W.
__global__ __launch_bounds__(256) void k_gtu(
    float* __restrict__ W, const float* __restrict__ x,
    const __bf16* __restrict__ Bh, const __bf16* __restrict__ Bm, const __bf16* __restrict__ Bl){
  __shared__ float xs[64][65];
  int d0 = blockIdx.x * 64;
  int m0 = blockIdx.y * 1024;
  int t = threadIdx.x;
  int lane = t & 63, wave = t >> 6;
  int kgrp = lane >> 4, lrow = lane & 15;
  int dloc = wave*16 + lrow;                    // this lane's column within the 64-wide tile
  f32x4 acc[4] = {};
  int r0 = t >> 2, c0 = (t & 3) * 16;           // load role: 4 threads x 16 floats per row
  for (int mc64 = m0; mc64 < m0 + 1024; mc64 += 64){
    __syncthreads();                            // previous chunk's reads done
    const float* gr = x + (size_t)(mc64 + r0)*4096 + d0 + c0;
    #pragma unroll
    for (int i = 0; i < 4; i++)
      *(float4*)&xs[r0][c0 + 4*i] = *(const float4*)(gr + 4*i);
    __syncthreads();
    #pragma unroll
    for (int half = 0; half < 2; half++){
      int mc = mc64 + half*32;
      bf16x8 ah, am, al;
      int kb = half*32 + kgrp*8;
      #pragma unroll
      for (int j = 0; j < 8; j++){
        float v = xs[kb + j][dloc];
        __bf16 h = (__bf16)v;
        float r1 = v - (float)h;
        __bf16 md = (__bf16)r1;
        float r2 = r1 - (float)md;
        ah[j] = h; am[j] = md; al[j] = (__bf16)r2;
      }
      #pragma unroll
      for (int n = 0; n < 4; n++){
        size_t bo = (size_t)(n*16 + lrow)*8192 + mc + kgrp*8;
        bf16x8 bh = *(const bf16x8*)(Bh + bo);
        bf16x8 bm = *(const bf16x8*)(Bm + bo);
        bf16x8 bl = *(const bf16x8*)(Bl + bo);
        acc[n] = __builtin_amdgcn_mfma_f32_16x16x32_bf16(ah, bh, acc[n],0,0,0);
        acc[n] = __builtin_amdgcn_mfma_f32_16x16x32_bf16(ah, bm, acc[n],0,0,0);
        acc[n] = __builtin_amdgcn_mfma_f32_16x16x32_bf16(am, bh, acc[n],0,0,0);
        acc[n] = __builtin_amdgcn_mfma_f32_16x16x32_bf16(ah, bl, acc[n],0,0,0);
        acc[n] = __builtin_amdgcn_mfma_f32_16x16x32_bf16(al, bh, acc[n],0,0,0);
        acc[n] = __builtin_amdgcn_mfma_f32_16x16x32_bf16(am, bm, acc[n],0,0,0);
      }
    }
  }
  #pragma unroll
  for (int n = 0; n < 4; n++)
    #pragma unroll
    for (int r = 0; r < 4; r++)
      atomicAdd(&W[(size_t)(d0 + wave*16 + kgrp*4 + r)*64 + n*16 + lrow], acc[n][r]);
}

// ---------------- Gram += Pchunk^T Pchunk   grid 64 ----------------
__global__ void k_gram(const float* __restrict__ P, float* __restrict__ Gram){
  __shared__ float Pt[128][65];
  int m0 = blockIdx.x * 128;
  int t = threadIdx.x;
  for (int i = 0; i < 32; i++){
    int idx = i*256 + t; int r = idx >> 6, c = idx & 63;
    Pt[r][c] = P[(size_t)(m0+r)*64 + c];
  }
  __syncthreads();
  int ti = t >> 4, tj = t & 15;
  float acc[4][4] = {};
  for (int r = 0; r < 128; r++){
    float a[4], b[4];
    #pragma unroll
    for (int q = 0; q < 4; q++) a[q] = Pt[r][ti*4+q];
    #pragma unroll
    for (int q = 0; q < 4; q++) b[q] = Pt[r][tj*4+q];
    #pragma unroll
    for (int xx = 0; xx < 4; xx++)
      #pragma unroll
      for (int y = 0; y < 4; y++) acc[xx][y] += a[xx]*b[y];
  }
  for (int xx = 0; xx < 4; xx++)
    for (int y = 0; y < 4; y++)
      atomicAdd(&Gram[(ti*4+xx)*64 + tj*4+y], acc[xx][y]);
}

// ---------------- fp64 Cholesky of Gram + lower-tri inverse ----------------
__global__ void k_cholinv(const float* __restrict__ Gram, float* __restrict__ Linv){
  __shared__ double A[64][64];
  __shared__ double Li[64][64];
  int t = threadIdx.x;
  for (int j = 0; j < 64; j++){ A[t][j] = (double)Gram[t*64+j]; Li[t][j] = 0.0; }
  __syncthreads();
  for (int k = 0; k < 64; k++){
    if (t == k) A[k][k] = sqrt(A[k][k]);
    __syncthreads();
    if (t > k) A[t][k] /= A[k][k];
    __syncthreads();
    if (t > k){
      double aik = A[t][k];
      for (int j = k+1; j <= t; j++) A[t][j] -= aik * A[j][k];
    }
    __syncthreads();
  }
  for (int i = t; i < 64; i++){
    double s = (i == t) ? 1.0 : 0.0;
    for (int p = t; p < i; p++) s -= A[i][p] * Li[p][t];
    Li[i][t] = s / A[i][i];
  }
  __syncthreads();
  for (int j = 0; j < 64; j++) Linv[t*64+j] = (float)Li[t][j];
}

// ---------------- U = P @ Linv^T   grid 128 ----------------
__global__ void k_applyq(float* __restrict__ U, const float* __restrict__ P,
                         const float* __restrict__ Linv){
  __shared__ float Pt[64][65];
  __shared__ float Lt[64][65];
  int m0 = blockIdx.x * 64;
  int t = threadIdx.x;
  for (int i = 0; i < 16; i++){
    int idx = i*256 + t; int r = idx >> 6, c = idx & 63;
    Pt[r][c] = P[(size_t)(m0+r)*64 + c];
    Lt[r][c] = Linv[r*64 + c];
  }
  __syncthreads();
  int tm = t >> 4, tj = t & 15;
  float acc[4][4] = {};
  for (int i = 0; i < 64; i++){
    float p[4], lv[4];
    #pragma unroll
    for (int a = 0; a < 4; a++) p[a]  = Pt[tm*4+a][i];
    #pragma unroll
    for (int b = 0; b < 4; b++) lv[b] = Lt[tj*4+b][i];
    #pragma unroll
    for (int a = 0; a < 4; a++)
      #pragma unroll
      for (int b = 0; b < 4; b++) acc[a][b] += p[a]*lv[b];
  }
  for (int a = 0; a < 4; a++)
    for (int b = 0; b < 4; b++)
      U[(size_t)(m0+tm*4+a)*64 + tj*4+b] = acc[a][b];
}

// ---------------- column norms of W[4096,64]  grid 64 ----------------
__global__ void k_colnorm(const float* __restrict__ W, float* __restrict__ cn){
  int k = blockIdx.x;
  float s = 0.f;
  for (int d = threadIdx.x; d < 4096; d += 256){
    float v = W[(size_t)d*64 + k];
    s += v*v;
  }
  for (int o = 32; o > 0; o >>= 1) s += __shfl_down(s, o, 64);
  __shared__ float sm[4];
  int lane = threadIdx.x & 63, w = threadIdx.x >> 6;
  if (lane == 0) sm[w] = s;
  __syncthreads();
  if (threadIdx.x == 0) cn[k] = sqrtf(sm[0]+sm[1]+sm[2]+sm[3]);
}

__global__ void k_vnorm(float* __restrict__ V, const float* __restrict__ W,
                        const float* __restrict__ cn){
  int i = blockIdx.x*256 + threadIdx.x;
  int k = i & 63;
  V[i] = W[i] / (cn[k] + EPSF);
}

// Vn = W/(S+EPS); KVT[d][k] = S*Vn (bf16 h/l); amax_v   grid 1024
__global__ void k_vnkv(float* __restrict__ V, __bf16* __restrict__ Kh, __bf16* __restrict__ Kl,
                       const float* __restrict__ W, const float* __restrict__ S,
                       unsigned* __restrict__ amaxv){
  int i = blockIdx.x*256 + threadIdx.x;
  int k = i & 63, d = i >> 6;
  float s = S[k];
  float vn = W[i] / (s + EPSF);
  V[i] = vn;
  float kv = s * vn;
  __bf16 h = (__bf16)kv;
  Kh[(size_t)d*64 + k] = h;
  Kl[(size_t)d*64 + k] = (__bf16)(kv - (float)h);
  float m = fabsf(vn);
  for (int o = 32; o > 0; o >>= 1) m = fmaxf(m, __shfl_down(m, o, 64));
  __shared__ float sm[4];
  int lane = threadIdx.x & 63, w = threadIdx.x >> 6;
  if (lane == 0) sm[w] = m;
  __syncthreads();
  if (threadIdx.x == 0)
    atomicMax(amaxv, __float_as_uint(fmaxf(fmaxf(sm[0],sm[1]), fmaxf(sm[2],sm[3]))));
}

// ---------------- transpose+3-split prep: Vc[4096,64] -> VcT h/m/l [64,4096]  grid 64 ----------------
__global__ void k_prep_vct(const float* __restrict__ Vc, __bf16* __restrict__ Th,
                           __bf16* __restrict__ Tm, __bf16* __restrict__ Tl){
  __shared__ float Vt[64][65];
  int d0 = blockIdx.x * 64;
  int t = threadIdx.x;
  for (int i = 0; i < 16; i++){
    int idx = i*256 + t; int r = idx >> 6, c = idx & 63;
    Vt[r][c] = Vc[(size_t)(d0 + r)*64 + c];
  }
  __syncthreads();
  for (int i = 0; i < 16; i++){
    int idx = i*256 + t; int k = idx >> 6, dd = idx & 63;
    float v = Vt[dd][k];
    __bf16 h = (__bf16)v;
    float r1 = v - (float)h;
    __bf16 md = (__bf16)r1;
    float r2 = r1 - (float)md;
    size_t o = (size_t)k*4096 + d0 + dd;
    Th[o] = h; Tm[o] = md; Tl[o] = (__bf16)r2;
  }
}

// prep U: Ub[8192,64] -> U h/l [8192,64] + UT h/m/l [64,8192]   grid 128
__global__ void k_prep_u(const float* __restrict__ Ub, __bf16* __restrict__ Uh, __bf16* __restrict__ Ul,
                         __bf16* __restrict__ Th, __bf16* __restrict__ Tm, __bf16* __restrict__ Tl){
  __shared__ float Ut[64][65];
  int m0 = blockIdx.x * 64;
  int t = threadIdx.x;
  for (int i = 0; i < 16; i++){
    int idx = i*256 + t; int r = idx >> 6, c = idx & 63;
    float v = Ub[(size_t)(m0 + r)*64 + c];
    Ut[r][c] = v;
    __bf16 h = (__bf16)v;
    Uh[(size_t)(m0+r)*64 + c] = h;
    Ul[(size_t)(m0+r)*64 + c] = (__bf16)(v - (float)h);
  }
  __syncthreads();
  for (int i = 0; i < 16; i++){
    int idx = i*256 + t; int k = idx >> 6, mm = idx & 63;
    float v = Ut[mm][k];
    __bf16 h = (__bf16)v;
    float r1 = v - (float)h;
    __bf16 md = (__bf16)r1;
    float r2 = r1 - (float)md;
    size_t o = (size_t)k*8192 + m0 + mm;
    Th[o] = h; Tm[o] = md; Tl[o] = (__bf16)r2;
  }
}

// ---------------- quantize weight -> Bq[:, :4096]  (float4)  grid 16384 ----------------
__global__ void k_qw(__bf16* __restrict__ Bq, const float* __restrict__ w,
                     const unsigned* __restrict__ amaxw){
  float s = fmaxf(__uint_as_float(*amaxw) / 6.0f, EPSF);
  int i = blockIdx.x*256 + threadIdx.x;          // 4.19M groups of 4
  int n = i >> 10, d = (i & 1023)*4;
  float4 v = *(const float4*)(w + (size_t)n*4096 + d);
  bf16x4 o;
  o[0] = (__bf16)qgrid(v.x, s); o[1] = (__bf16)qgrid(v.y, s);
  o[2] = (__bf16)qgrid(v.z, s); o[3] = (__bf16)qgrid(v.w, s);
  *(bf16x4*)(Bq + (size_t)n*4160 + d) = o;
}

// ---------------- quantize U -> Aq[:, 4096:4160]  grid 2048 ----------------
__global__ void k_qu(__bf16* __restrict__ Aq, const float* __restrict__ U,
                     const unsigned* __restrict__ amaxu){
  float s = fmaxf(__uint_as_float(*amaxu) / 6.0f, EPSF);
  int i = blockIdx.x*256 + threadIdx.x;
  int m = i >> 6, k = i & 63;
  Aq[(size_t)m*4160 + 4096 + k] = (__bf16)qgrid(U[i], s);
}

// ---------------- quantize V -> Vq[k][d] (LDS transpose)  grid 64 ----------------
__global__ void k_qv(__bf16* __restrict__ Vq, const float* __restrict__ V,
                     const unsigned* __restrict__ amaxv){
  __shared__ float Vt[64][65];
  float s = fmaxf(__uint_as_float(*amaxv)/6.0f, EPSF);
  int d0 = blockIdx.x * 64;
  int t = threadIdx.x;
  for (int i = 0; i < 16; i++){
    int idx = i*256 + t; int r = idx >> 6, c = idx & 63;
    Vt[r][c] = V[(size_t)(d0 + r)*64 + c];
  }
  __syncthreads();
  for (int i = 0; i < 16; i++){
    int idx = i*256 + t; int k = idx >> 6, dd = idx & 63;
    Vq[(size_t)k*4096 + d0 + dd] = (__bf16)qgrid(Vt[dd][k], s);
  }
}

// ---------------- residual: ker = U@KV via 2-split MFMA; amax or quantize  grid(128,32) ----------------
__global__ __launch_bounds__(256) void k_res(
    const float* __restrict__ x, const __bf16* __restrict__ Uh, const __bf16* __restrict__ Ul,
    const __bf16* __restrict__ Kh, const __bf16* __restrict__ Kl,
    unsigned* __restrict__ amaxr, __bf16* __restrict__ Aq, int mode){
  int m0 = blockIdx.x * 64, n0 = blockIdx.y * 128;
  int lane = threadIdx.x & 63, wave = threadIdx.x >> 6;
  int kgrp = lane >> 4, lrow = lane & 15;
  int mrow = m0 + wave*16 + lrow;
  f32x4 acc[8] = {};
  #pragma unroll
  for (int ks = 0; ks < 2; ks++){
    size_t ao = (size_t)mrow*64 + ks*32 + kgrp*8;
    bf16x8 uh = *(const bf16x8*)(Uh + ao);
    bf16x8 ul = *(const bf16x8*)(Ul + ao);
    #pragma unroll
    for (int n = 0; n < 8; n++){
      size_t bo = (size_t)(n0 + n*16 + lrow)*64 + ks*32 + kgrp*8;
      bf16x8 kh = *(const bf16x8*)(Kh + bo);
      bf16x8 kl = *(const bf16x8*)(Kl + bo);
      acc[n] = __builtin_amdgcn_mfma_f32_16x16x32_bf16(uh, kh, acc[n],0,0,0);
      acc[n] = __builtin_amdgcn_mfma_f32_16x16x32_bf16(uh, kl, acc[n],0,0,0);
      acc[n] = __builtin_amdgcn_mfma_f32_16x16x32_bf16(ul, kh, acc[n],0,0,0);
    }
  }
  int mb = m0 + wave*16 + kgrp*4;
  if (mode == 0){
    float mx = 0.f;
    #pragma unroll
    for (int n = 0; n < 8; n++){
      int c = n0 + n*16 + lrow;
      #pragma unroll
      for (int r = 0; r < 4; r++)
        mx = fmaxf(mx, fabsf(x[(size_t)(mb + r)*4096 + c] - acc[n][r]));
    }
    for (int o = 32; o > 0; o >>= 1) mx = fmaxf(mx, __shfl_down(mx, o, 64));
    __shared__ float sm[4];
    if (lane == 0) sm[wave] = mx;
    __syncthreads();
    if (threadIdx.x == 0)
      atomicMax(amaxr, __float_as_uint(fmaxf(fmaxf(sm[0],sm[1]), fmaxf(sm[2],sm[3]))));
  } else {
    float s = fmaxf(__uint_as_float(*amaxr)/6.0f, EPSF);
    #pragma unroll
    for (int n = 0; n < 8; n++){
      int c = n0 + n*16 + lrow;
      #pragma unroll
      for (int r = 0; r < 4; r++)
        Aq[(size_t)(mb + r)*4160 + c] =
          (__bf16)qgrid(x[(size_t)(mb + r)*4096 + c] - acc[n][r], s);
    }
  }
}

// ---------------- M1 += Vq @ Wq^T  (exact bf16 MFMA)  grid(64,8) ----------------
__global__ __launch_bounds__(256) void k_m1(
    float* __restrict__ M1g, const __bf16* __restrict__ Vq, const __bf16* __restrict__ Bq){
  int n0 = blockIdx.x * 64;
  int k0 = blockIdx.y * 512;
  int lane = threadIdx.x & 63, wave = threadIdx.x >> 6;
  int kgrp = lane >> 4, lrow = lane & 15;
  int nrow = n0 + wave*16 + lrow;
  f32x4 acc[4] = {};
  for (int kc = k0; kc < k0 + 512; kc += 32){
    bf16x8 fb = *(const bf16x8*)(Bq + (size_t)nrow*4160 + kc + kgrp*8);
    #pragma unroll
    for (int mt = 0; mt < 4; mt++){
      bf16x8 fa = *(const bf16x8*)(Vq + (size_t)(mt*16 + lrow)*4096 + kc + kgrp*8);
      acc[mt] = __builtin_amdgcn_mfma_f32_16x16x32_bf16(fa, fb, acc[mt],0,0,0);
    }
  }
  #pragma unroll
  for (int mt = 0; mt < 4; mt++)
    #pragma unroll
    for (int r = 0; r < 4; r++)
      atomicAdd(&M1g[(size_t)(mt*16 + kgrp*4 + r)*4096 + nrow], acc[mt][r]);
}

// ---------------- M2T: Bq[:, 4096:4160] = M1[k][n] * su*sv*S[k]/sr  grid 1024 ----------------
__global__ void k_m2t(__bf16* __restrict__ Bq, const float* __restrict__ M1g,
                      const float* __restrict__ S, const unsigned* __restrict__ scal){
  float su = fmaxf(__uint_as_float(scal[1])/6.0f, EPSF);
  float sv = fmaxf(__uint_as_float(scal[2])/6.0f, EPSF);
  float sr = fmaxf(__uint_as_float(scal[3])/6.0f, EPSF);
  int i = blockIdx.x*256 + threadIdx.x;
  int n = i >> 6, k = i & 63;
  float v = M1g[(size_t)k*4096 + n] * (su * sv * S[k] / sr);
  Bq[(size_t)n*4160 + 4096 + k] = (__bf16)v;
}

// ---------------- main bf16 MFMA GEMM: out = (A @ B^T)*sr*sw + bias ----------------
// 256x256 tile, BK=32, 512 threads (8 waves, 2Mx4N), 4-deep LDS ring (128 KiB).
// Counted s_waitcnt vmcnt(8) + builtin s_barrier, setprio around MFMA cluster,
// nontemporal epilogue stores. Verified best at ~237 us (R4).
__global__ __launch_bounds__(512, 2)
void k_gemm(float* __restrict__ out, const __bf16* __restrict__ A,
            const __bf16* __restrict__ B, const float* __restrict__ bias,
            const unsigned* __restrict__ scal){
  __shared__ __align__(16) __bf16 As[4*8192];   // 4 ring slots x 128 packed rows x 64 el
  __shared__ __align__(16) __bf16 Bs[4*8192];
  const int m0 = blockIdx.y * 256, n0 = blockIdx.x * 256;
  const int tid = threadIdx.x;
  const int lane = tid & 63, wave = tid >> 6;
  const int wrow = wave >> 2, wcol = wave & 3;     // 2 x 4 wave grid
  const int kg = lane >> 4, lr = lane & 15;
  f32x4 acc[8][4] = {};

  auto STAGE = [&](int tt){
    __bf16* as = &As[(tt & 3) * 8192];
    __bf16* bs = &Bs[(tt & 3) * 8192];
    const int kt = tt * 32;
    #pragma unroll
    for (int q = 0; q < 2; q++){
      int idx = q * 512 + tid;                 // 1024 16B-slots per matrix
      int rp  = idx >> 3;                      // packed LDS row 0..127
      int sp  = (idx & 7) ^ (rp & 7);          // unswizzled slot
      int grow = rp * 2 + (sp >> 2);           // global tile row 0..255
      int gcol = (sp & 3) * 8;                 // global k element 0..24
      const __bf16* ga = A + (size_t)(m0 + grow) * KT + kt + gcol;
      const __bf16* gb = B + (size_t)(n0 + grow) * KT + kt + gcol;
      __bf16* la = as + (size_t)(idx & ~63) * 8;
      __bf16* lb = bs + (size_t)(idx & ~63) * 8;
      __builtin_amdgcn_global_load_lds((const __attribute__((address_space(1))) uint32_t*)ga,
                                       (__attribute__((address_space(3))) uint32_t*)la, 16, 0, 0);
      __builtin_amdgcn_global_load_lds((const __attribute__((address_space(1))) uint32_t*)gb,
                                       (__attribute__((address_space(3))) uint32_t*)lb, 16, 0, 0);
    }
  };

  auto BODY = [&](int t, bool stage){
    const __bf16* as = &As[(t & 3) * 8192];
    const __bf16* bs = &Bs[(t & 3) * 8192];
    bf16x8 fa[8], fb[4];
    #pragma unroll
    for (int mf = 0; mf < 8; mf++){
      int row = wrow*128 + mf*16 + lr;
      int rp  = row >> 1;
      int sl  = (((row & 1) << 2) | kg) ^ (rp & 7);
      fa[mf] = *(const bf16x8*)(as + (size_t)rp*64 + sl*8);
    }
    #pragma unroll
    for (int nf = 0; nf < 4; nf++){
      int row = wcol*64 + nf*16 + lr;
      int rp  = row >> 1;
      int sl  = (((row & 1) << 2) | kg) ^ (rp & 7);
      fb[nf] = *(const bf16x8*)(bs + (size_t)rp*64 + sl*8);
    }
    if (stage) STAGE(t + 3);                    // slot (t+3)&3: last read at iter t-1, safe
    __builtin_amdgcn_s_setprio(1);
    #pragma unroll
    for (int mf = 0; mf < 8; mf++)
      #pragma unroll
      for (int nf = 0; nf < 4; nf++)
        acc[mf][nf] = __builtin_amdgcn_mfma_f32_16x16x32_bf16(fa[mf], fb[nf], acc[mf][nf], 0, 0, 0);
    __builtin_amdgcn_s_setprio(0);
  };

  STAGE(0); STAGE(1); STAGE(2);                // prologue: 3 tiles (12 loads) in flight

  const int NT = KT / 32;                      // 130
  for (int t = 0; t < NT - 2; t++){
    asm volatile("s_waitcnt vmcnt(8)" ::: "memory");
    __builtin_amdgcn_s_barrier();
    BODY(t, t < NT - 3);
  }
  asm volatile("s_waitcnt vmcnt(4)" ::: "memory");
  __builtin_amdgcn_s_barrier();
  BODY(NT - 2, false);
  asm volatile("s_waitcnt vmcnt(0)" ::: "memory");
  __builtin_amdgcn_s_barrier();
  BODY(NT - 1, false);

  float sr = fmaxf(__uint_as_float(scal[3])/6.0f, EPSF);
  float sw = fmaxf(__uint_as_float(scal[0])/6.0f, EPSF);
  float srw = sr * sw;
  #pragma unroll
  for (int nf = 0; nf < 4; nf++){
    int n = n0 + wcol*64 + nf*16 + lr;
    float bv = bias[n];
    #pragma unroll
    for (int mf = 0; mf < 8; mf++){
      int mb = m0 + wrow*128 + mf*16 + 4*kg;
      #pragma unroll
      for (int r = 0; r < 4; r++)
        __builtin_nontemporal_store(acc[mf][nf][r]*srw + bv,
                                    &out[(size_t)(mb + r)*4096 + n]);
    }
  }
}

// ---------------- host side ----------------
extern "C" void kernel_launch(void* const* d_in, const int* in_sizes, int n_in,
                              void* d_out, int out_size, void* d_ws, size_t ws_size,
                              hipStream_t stream){
  const float* x    = (const float*)d_in[0];   // [8192, 4096]
  const float* wt   = (const float*)d_in[1];   // [4096, 4096]
  const float* bias = (const float*)d_in[2];   // [4096]
  const float* V0   = (const float*)d_in[3];   // [4096, 64]
  float* out = (float*)d_out;
  if (ws_size < WS_NEED) return;

  float* F = (float*)d_ws;
  unsigned* scal = (unsigned*)(F + oScal);
  __bf16* BFp = (__bf16*)((char*)d_ws + bfByte);
  __bf16* Vq  = BFp + oVq;
  __bf16* Aq  = BFp + oA;
  __bf16* Bq  = BFp + oB;
  __bf16* VcTh = BFp + oVcT,              *VcTm = VcTh + (size_t)64*4096, *VcTl = VcTm + (size_t)64*4096;
  __bf16* UTh  = BFp + oUT,               *UTm  = UTh + (size_t)64*8192,  *UTl  = UTm + (size_t)64*8192;
  __bf16* Uh   = BFp + oUhl,              *Ul   = Uh + (size_t)8192*64;
  __bf16* KVTh = BFp + oKVT,              *KVTl = KVTh + (size_t)4096*64;
  float *P = F+oP, *W = F+oW, *Gm = F+oG, *M1 = F+oM1, *Sv = F+oS,
        *Li = F+oLinv, *V = F+oV, *Ub = F+oU;

  dim3 b256(256);
  k_zero <<<dim3(2048), b256, 0, stream>>>(F, (int)nZero1);
  k_amax4<<<dim3(1024), b256, 0, stream>>>((const float4*)wt, 4194304, scal+0);
  k_qw   <<<dim3(16384), b256, 0, stream>>>(Bq, wt, scal+0);

  // ---- power iteration 1 ----
  k_prep_vct<<<dim3(64),  b256, 0, stream>>>(V0, VcTh, VcTm, VcTl);
  k_gv     <<<dim3(64,8), b256, 0, stream>>>(P, x, VcTh, VcTm, VcTl);
  k_gram   <<<dim3(64),   b256, 0, stream>>>(P, Gm);
  k_cholinv<<<dim3(1), dim3(64), 0, stream>>>(Gm, Li);
  k_applyq <<<dim3(128),  b256, 0, stream>>>(Ub, P, Li);
  k_prep_u <<<dim3(128),  b256, 0, stream>>>(Ub, Uh, Ul, UTh, UTm, UTl);
  k_gtu    <<<dim3(64,8), b256, 0, stream>>>(W, x, UTh, UTm, UTl);
  k_colnorm<<<dim3(64),   b256, 0, stream>>>(W, Sv);
  k_vnorm  <<<dim3(1024), b256, 0, stream>>>(V, W, Sv);

  // ---- power iteration 2 ----
  k_prep_vct<<<dim3(64),  b256, 0, stream>>>(V, VcTh, VcTm, VcTl);
  k_zero   <<<dim3(2048), b256, 0, stream>>>(F, (int)nZero2);      // P, W, Gram
  k_gv     <<<dim3(64,8), b256, 0, stream>>>(P, x, VcTh, VcTm, VcTl);
  k_gram   <<<dim3(64),   b256, 0, stream>>>(P, Gm);
  k_cholinv<<<dim3(1), dim3(64), 0, stream>>>(Gm, Li);
  k_applyq <<<dim3(128),  b256, 0, stream>>>(Ub, P, Li);
  k_prep_u <<<dim3(128),  b256, 0, stream>>>(Ub, Uh, Ul, UTh, UTm, UTl);
  k_gtu    <<<dim3(64,8), b256, 0, stream>>>(W, x, UTh, UTm, UTl);
  k_colnorm<<<dim3(64),   b256, 0, stream>>>(W, Sv);               // Sv = S
  k_vnkv   <<<dim3(1024), b256, 0, stream>>>(V, KVTh, KVTl, W, Sv, scal+2);

  // ---- quantize factors + residual ----
  k_amax4<<<dim3(1024), b256, 0, stream>>>((const float4*)Ub, 131072, scal+1);
  k_qu   <<<dim3(2048), b256, 0, stream>>>(Aq, Ub, scal+1);
  k_qv   <<<dim3(64),   b256, 0, stream>>>(Vq, V, scal+2);
  k_res  <<<dim3(128,32), b256, 0, stream>>>(x, Uh, Ul, KVTh, KVTl, scal+3, Aq, 0);
  k_res  <<<dim3(128,32), b256, 0, stream>>>(x, Uh, Ul, KVTh, KVTl, scal+3, Aq, 1);

  // ---- low-rank fold + main GEMM ----
  k_m1  <<<dim3(64,8), b256, 0, stream>>>(M1, Vq, Bq);
  k_m2t <<<dim3(1024), b256, 0, stream>>>(Bq, M1, Sv, scal);
  k_gemm<<<dim3(16,32), dim3(512), 0, stream>>>(out, Aq, Bq, bias, scal);
}

// Round 8
// 1436.141 us; speedup vs baseline: 1.1800x; 1.0116x over previous
//
#include <hip/hip_runtime.h>
#include <stdint.h>

#define EPSF 1e-8f
#define KT 4160

typedef float  f32x4  __attribute__((ext_vector_type(4)));
typedef __bf16 bf16x8 __attribute__((ext_vector_type(8)));
typedef __bf16 bf16x4 __attribute__((ext_vector_type(4)));

// ---------------- workspace layout ----------------
// fp32 region (element offsets)
constexpr size_t oP    = 0;                     // P   [8192*64]
constexpr size_t oW    = oP  + 8192*64;         // W   [4096*64]
constexpr size_t oG    = oW  + 4096*64;         // Gram[64*64]
constexpr size_t oM1   = oG  + 64*64;           // M1  [64*4096]
constexpr size_t oScal = oM1 + 64*4096;         // 4 u32: amax_w, amax_u, amax_v, amax_r
constexpr size_t nZero1= oScal + 4;             // initial zero: P,W,G,M1,scal
constexpr size_t nZero2= oG + 64*64;            // iter-2 zero: P,W,G
constexpr size_t oS    = nZero1;                // 64
constexpr size_t oLinv = oS + 64;               // 64*64
constexpr size_t oV    = oLinv + 64*64;         // V  [4096*64]
constexpr size_t oU    = oV + 4096*64;          // Ub [8192*64]
constexpr size_t endF32= oU + 8192*64;
constexpr size_t bfByte= ((endF32*4 + 255)/256)*256;
// bf16 region (element offsets)
constexpr size_t oVq   = 0;                     // Vq [64*4096]
constexpr size_t oA    = oVq + 64*4096;         // A = [Rq | Uq]  [8192*4160]
constexpr size_t oB    = oA + (size_t)8192*4160;// B = [Wq | M2T] [4096*4160]
constexpr size_t oVcT  = oB + (size_t)4096*4160;// VcT h/m/l 3x[64*4096]
constexpr size_t oUT   = oVcT + 3*(size_t)64*4096;   // UT h/m/l 3x[64*8192]
constexpr size_t oUhl  = oUT + 3*(size_t)64*8192;    // U h/l 2x[8192*64]
constexpr size_t oKVT  = oUhl + 2*(size_t)8192*64;   // KVT h/l 2x[4096*64]
constexpr size_t endBF = oKVT + 2*(size_t)4096*64;
constexpr size_t WS_NEED = bfByte + endBF*2;

// ---------------- fp4 e2m1 helpers ----------------
__device__ __forceinline__ float qlevel(float a){
  if (a <= 0.25f) return 0.0f;
  if (a <= 0.75f) return 0.5f;
  if (a <= 1.25f) return 1.0f;
  if (a <= 1.75f) return 1.5f;
  if (a <= 2.5f)  return 2.0f;
  if (a <= 3.5f)  return 3.0f;
  if (a <= 5.0f)  return 4.0f;
  return 6.0f;
}
__device__ __forceinline__ float qgrid(float v, float s){
  float y = v / s;
  float l = qlevel(fabsf(y));
  return y < 0.0f ? -l : l;
}

// ---------------- utility ----------------
__global__ void k_zero(float* p, int n){
  for (int i = blockIdx.x*blockDim.x + threadIdx.x; i < n; i += gridDim.x*blockDim.x)
    p[i] = 0.0f;
}

__global__ void k_amax4(const float4* __restrict__ x, int n4, unsigned* __restrict__ out){
  float m = 0.f;
  for (int i = blockIdx.x*blockDim.x + threadIdx.x; i < n4; i += gridDim.x*blockDim.x){
    float4 v = x[i];
    m = fmaxf(m, fmaxf(fmaxf(fabsf(v.x), fabsf(v.y)), fmaxf(fabsf(v.z), fabsf(v.w))));
  }
  for (int o = 32; o > 0; o >>= 1) m = fmaxf(m, __shfl_down(m, o, 64));
  __shared__ float sm[4];
  int lane = threadIdx.x & 63, w = threadIdx.x >> 6;
  if (lane == 0) sm[w] = m;
  __syncthreads();
  if (threadIdx.x == 0)
    atomicMax(out, __float_as_uint(fmaxf(fmaxf(sm[0],sm[1]), fmaxf(sm[2],sm[3]))));
}

// ---------------- P += x @ Vc  via 3-word-split bf16 MFMA  grid(64,8) ----------------
// A-frags register-assembled from fp32 x; B = VcT h/m/l [64,4096] bf16.
__global__ __launch_bounds__(256) void k_gv(
    float* __restrict__ P, const float* __restrict__ x,
    const __bf16* __restrict__ Bh, const __bf16* __restrict__ Bm, const __bf16* __restrict__ Bl){
  int m0 = blockIdx.x * 128;
  int d0 = blockIdx.y * 512;
  int lane = threadIdx.x & 63, wave = threadIdx.x >> 6;
  int kgrp = lane >> 4, lrow = lane & 15;
  f32x4 acc[2][4] = {};
  for (int dc = d0; dc < d0 + 512; dc += 32){
    bf16x8 ah[2], am[2], al[2];
    #pragma unroll
    for (int f = 0; f < 2; f++){
      const float* g = x + (size_t)(m0 + wave*32 + f*16 + lrow)*4096 + dc + kgrp*8;
      float4 a = *(const float4*)g;
      float4 b = *(const float4*)(g + 4);
      float v[8] = {a.x,a.y,a.z,a.w,b.x,b.y,b.z,b.w};
      #pragma unroll
      for (int j = 0; j < 8; j++){
        __bf16 h = (__bf16)v[j];
        float r1 = v[j] - (float)h;
        __bf16 md = (__bf16)r1;
        float r2 = r1 - (float)md;
        ah[f][j] = h; am[f][j] = md; al[f][j] = (__bf16)r2;
      }
    }
    #pragma unroll
    for (int n = 0; n < 4; n++){
      size_t bo = (size_t)(n*16 + lrow)*4096 + dc + kgrp*8;
      bf16x8 bh = *(const bf16x8*)(Bh + bo);
      bf16x8 bm = *(const bf16x8*)(Bm + bo);
      bf16x8 bl = *(const bf16x8*)(Bl + bo);
      #pragma unroll
      for (int f = 0; f < 2; f++){
        acc[f][n] = __builtin_amdgcn_mfma_f32_16x16x32_bf16(ah[f], bh, acc[f][n],0,0,0);
        acc[f][n] = __builtin_amdgcn_mfma_f32_16x16x32_bf16(ah[f], bm, acc[f][n],0,0,0);
        acc[f][n] = __builtin_amdgcn_mfma_f32_16x16x32_bf16(am[f], bh, acc[f][n],0,0,0);
        acc[f][n] = __builtin_amdgcn_mfma_f32_16x16x32_bf16(ah[f], bl, acc[f][n],0,0,0);
        acc[f][n] = __builtin_amdgcn_mfma_f32_16x16x32_bf16(al[f], bh, acc[f][n],0,0,0);
        acc[f][n] = __builtin_amdgcn_mfma_f32_16x16x32_bf16(am[f], bm, acc[f][n],0,0,0);
      }
    }
  }
  #pragma unroll
  for (int f = 0; f < 2; f++)
    #pragma unroll
    for (int n = 0; n < 4; n++)
      #pragma unroll
      for (int r = 0; r < 4; r++)
        atomicAdd(&P[(size_t)(m0 + wave*32 + f*16 + kgrp*4 + r)*64 + n*16 + lrow], acc[f][n][r]);
}

// ---------------- W += x^T @ U  (LDS-transposed x, coalesced loads)  grid(64,8) ----------------
__global__ __launch_bounds__(256) void k_gtu(
    float* __restrict__ W, const float* __restrict__ x,
    const __bf16* __restrict__ Bh, const __bf16* __restrict__ Bm, const __bf16* __restrict__ Bl){
  __shared__ float xs[64][65];
  int d0 = blockIdx.x * 64;
  int m0 = blockIdx.y * 1024;
  int t = threadIdx.x;
  int lane = t & 63, wave = t >> 6;
  int kgrp = lane >> 4, lrow = lane & 15;
  int dloc = wave*16 + lrow;                    // this lane's column within the 64-wide tile
  f32x4 acc[4] = {};
  int r0 = t >> 2, c0 = (t & 3) * 16;           // load role: 4 threads x 16 floats per row
  for (int mc64 = m0; mc64 < m0 + 1024; mc64 += 64){
    __syncthreads();                            // previous chunk's reads done
    const float* gr = x + (size_t)(mc64 + r0)*4096 + d0 + c0;
    #pragma unroll
    for (int i = 0; i < 4; i++)
      *(float4*)&xs[r0][c0 + 4*i] = *(const float4*)(gr + 4*i);
    __syncthreads();
    #pragma unroll
    for (int half = 0; half < 2; half++){
      int mc = mc64 + half*32;
      bf16x8 ah, am, al;
      int kb = half*32 + kgrp*8;
      #pragma unroll
      for (int j = 0; j < 8; j++){
        float v = xs[kb + j][dloc];
        __bf16 h = (__bf16)v;
        float r1 = v - (float)h;
        __bf16 md = (__bf16)r1;
        float r2 = r1 - (float)md;
        ah[j] = h; am[j] = md; al[j] = (__bf16)r2;
      }
      #pragma unroll
      for (int n = 0; n < 4; n++){
        size_t bo = (size_t)(n*16 + lrow)*8192 + mc + kgrp*8;
        bf16x8 bh = *(const bf16x8*)(Bh + bo);
        bf16x8 bm = *(const bf16x8*)(Bm + bo);
        bf16x8 bl = *(const bf16x8*)(Bl + bo);
        acc[n] = __builtin_amdgcn_mfma_f32_16x16x32_bf16(ah, bh, acc[n],0,0,0);
        acc[n] = __builtin_amdgcn_mfma_f32_16x16x32_bf16(ah, bm, acc[n],0,0,0);
        acc[n] = __builtin_amdgcn_mfma_f32_16x16x32_bf16(am, bh, acc[n],0,0,0);
        acc[n] = __builtin_amdgcn_mfma_f32_16x16x32_bf16(ah, bl, acc[n],0,0,0);
        acc[n] = __builtin_amdgcn_mfma_f32_16x16x32_bf16(al, bh, acc[n],0,0,0);
        acc[n] = __builtin_amdgcn_mfma_f32_16x16x32_bf16(am, bm, acc[n],0,0,0);
      }
    }
  }
  #pragma unroll
  for (int n = 0; n < 4; n++)
    #pragma unroll
    for (int r = 0; r < 4; r++)
      atomicAdd(&W[(size_t)(d0 + wave*16 + kgrp*4 + r)*64 + n*16 + lrow], acc[n][r]);
}

// ---------------- Gram += Pchunk^T Pchunk   grid 64 ----------------
__global__ void k_gram(const float* __restrict__ P, float* __restrict__ Gram){
  __shared__ float Pt[128][65];
  int m0 = blockIdx.x * 128;
  int t = threadIdx.x;
  for (int i = 0; i < 32; i++){
    int idx = i*256 + t; int r = idx >> 6, c = idx & 63;
    Pt[r][c] = P[(size_t)(m0+r)*64 + c];
  }
  __syncthreads();
  int ti = t >> 4, tj = t & 15;
  float acc[4][4] = {};
  for (int r = 0; r < 128; r++){
    float a[4], b[4];
    #pragma unroll
    for (int q = 0; q < 4; q++) a[q] = Pt[r][ti*4+q];
    #pragma unroll
    for (int q = 0; q < 4; q++) b[q] = Pt[r][tj*4+q];
    #pragma unroll
    for (int xx = 0; xx < 4; xx++)
      #pragma unroll
      for (int y = 0; y < 4; y++) acc[xx][y] += a[xx]*b[y];
  }
  for (int xx = 0; xx < 4; xx++)
    for (int y = 0; y < 4; y++)
      atomicAdd(&Gram[(ti*4+xx)*64 + tj*4+y], acc[xx][y]);
}

// ---------------- fp64 Cholesky of Gram + lower-tri inverse ----------------
__global__ void k_cholinv(const float* __restrict__ Gram, float* __restrict__ Linv){
  __shared__ double A[64][64];
  __shared__ double Li[64][64];
  int t = threadIdx.x;
  for (int j = 0; j < 64; j++){ A[t][j] = (double)Gram[t*64+j]; Li[t][j] = 0.0; }
  __syncthreads();
  for (int k = 0; k < 64; k++){
    if (t == k) A[k][k] = sqrt(A[k][k]);
    __syncthreads();
    if (t > k) A[t][k] /= A[k][k];
    __syncthreads();
    if (t > k){
      double aik = A[t][k];
      for (int j = k+1; j <= t; j++) A[t][j] -= aik * A[j][k];
    }
    __syncthreads();
  }
  for (int i = t; i < 64; i++){
    double s = (i == t) ? 1.0 : 0.0;
    for (int p = t; p < i; p++) s -= A[i][p] * Li[p][t];
    Li[i][t] = s / A[i][i];
  }
  __syncthreads();
  for (int j = 0; j < 64; j++) Linv[t*64+j] = (float)Li[t][j];
}

// ---------------- U = P @ Linv^T   grid 128 ----------------
__global__ void k_applyq(float* __restrict__ U, const float* __restrict__ P,
                         const float* __restrict__ Linv){
  __shared__ float Pt[64][65];
  __shared__ float Lt[64][65];
  int m0 = blockIdx.x * 64;
  int t = threadIdx.x;
  for (int i = 0; i < 16; i++){
    int idx = i*256 + t; int r = idx >> 6, c = idx & 63;
    Pt[r][c] = P[(size_t)(m0+r)*64 + c];
    Lt[r][c] = Linv[r*64 + c];
  }
  __syncthreads();
  int tm = t >> 4, tj = t & 15;
  float acc[4][4] = {};
  for (int i = 0; i < 64; i++){
    float p[4], lv[4];
    #pragma unroll
    for (int a = 0; a < 4; a++) p[a]  = Pt[tm*4+a][i];
    #pragma unroll
    for (int b = 0; b < 4; b++) lv[b] = Lt[tj*4+b][i];
    #pragma unroll
    for (int a = 0; a < 4; a++)
      #pragma unroll
      for (int b = 0; b < 4; b++) acc[a][b] += p[a]*lv[b];
  }
  for (int a = 0; a < 4; a++)
    for (int b = 0; b < 4; b++)
      U[(size_t)(m0+tm*4+a)*64 + tj*4+b] = acc[a][b];
}

// ---------------- column norms of W[4096,64]  grid 64 ----------------
__global__ void k_colnorm(const float* __restrict__ W, float* __restrict__ cn){
  int k = blockIdx.x;
  float s = 0.f;
  for (int d = threadIdx.x; d < 4096; d += 256){
    float v = W[(size_t)d*64 + k];
    s += v*v;
  }
  for (int o = 32; o > 0; o >>= 1) s += __shfl_down(s, o, 64);
  __shared__ float sm[4];
  int lane = threadIdx.x & 63, w = threadIdx.x >> 6;
  if (lane == 0) sm[w] = s;
  __syncthreads();
  if (threadIdx.x == 0) cn[k] = sqrtf(sm[0]+sm[1]+sm[2]+sm[3]);
}

__global__ void k_vnorm(float* __restrict__ V, const float* __restrict__ W,
                        const float* __restrict__ cn){
  int i = blockIdx.x*256 + threadIdx.x;
  int k = i & 63;
  V[i] = W[i] / (cn[k] + EPSF);
}

// Vn = W/(S+EPS); KVT[d][k] = S*Vn (bf16 h/l); amax_v   grid 1024
__global__ void k_vnkv(float* __restrict__ V, __bf16* __restrict__ Kh, __bf16* __restrict__ Kl,
                       const float* __restrict__ W, const float* __restrict__ S,
                       unsigned* __restrict__ amaxv){
  int i = blockIdx.x*256 + threadIdx.x;
  int k = i & 63, d = i >> 6;
  float s = S[k];
  float vn = W[i] / (s + EPSF);
  V[i] = vn;
  float kv = s * vn;
  __bf16 h = (__bf16)kv;
  Kh[(size_t)d*64 + k] = h;
  Kl[(size_t)d*64 + k] = (__bf16)(kv - (float)h);
  float m = fabsf(vn);
  for (int o = 32; o > 0; o >>= 1) m = fmaxf(m, __shfl_down(m, o, 64));
  __shared__ float sm[4];
  int lane = threadIdx.x & 63, w = threadIdx.x >> 6;
  if (lane == 0) sm[w] = m;
  __syncthreads();
  if (threadIdx.x == 0)
    atomicMax(amaxv, __float_as_uint(fmaxf(fmaxf(sm[0],sm[1]), fmaxf(sm[2],sm[3]))));
}

// ---------------- transpose+3-split prep: Vc[4096,64] -> VcT h/m/l [64,4096]  grid 64 ----------------
__global__ void k_prep_vct(const float* __restrict__ Vc, __bf16* __restrict__ Th,
                           __bf16* __restrict__ Tm, __bf16* __restrict__ Tl){
  __shared__ float Vt[64][65];
  int d0 = blockIdx.x * 64;
  int t = threadIdx.x;
  for (int i = 0; i < 16; i++){
    int idx = i*256 + t; int r = idx >> 6, c = idx & 63;
    Vt[r][c] = Vc[(size_t)(d0 + r)*64 + c];
  }
  __syncthreads();
  for (int i = 0; i < 16; i++){
    int idx = i*256 + t; int k = idx >> 6, dd = idx & 63;
    float v = Vt[dd][k];
    __bf16 h = (__bf16)v;
    float r1 = v - (float)h;
    __bf16 md = (__bf16)r1;
    float r2 = r1 - (float)md;
    size_t o = (size_t)k*4096 + d0 + dd;
    Th[o] = h; Tm[o] = md; Tl[o] = (__bf16)r2;
  }
}

// prep U: Ub[8192,64] -> U h/l [8192,64] + UT h/m/l [64,8192]   grid 128
__global__ void k_prep_u(const float* __restrict__ Ub, __bf16* __restrict__ Uh, __bf16* __restrict__ Ul,
                         __bf16* __restrict__ Th, __bf16* __restrict__ Tm, __bf16* __restrict__ Tl){
  __shared__ float Ut[64][65];
  int m0 = blockIdx.x * 64;
  int t = threadIdx.x;
  for (int i = 0; i < 16; i++){
    int idx = i*256 + t; int r = idx >> 6, c = idx & 63;
    float v = Ub[(size_t)(m0 + r)*64 + c];
    Ut[r][c] = v;
    __bf16 h = (__bf16)v;
    Uh[(size_t)(m0+r)*64 + c] = h;
    Ul[(size_t)(m0+r)*64 + c] = (__bf16)(v - (float)h);
  }
  __syncthreads();
  for (int i = 0; i < 16; i++){
    int idx = i*256 + t; int k = idx >> 6, mm = idx & 63;
    float v = Ut[mm][k];
    __bf16 h = (__bf16)v;
    float r1 = v - (float)h;
    __bf16 md = (__bf16)r1;
    float r2 = r1 - (float)md;
    size_t o = (size_t)k*8192 + m0 + mm;
    Th[o] = h; Tm[o] = md; Tl[o] = (__bf16)r2;
  }
}

// ---------------- quantize weight -> Bq[:, :4096]  (float4)  grid 16384 ----------------
__global__ void k_qw(__bf16* __restrict__ Bq, const float* __restrict__ w,
                     const unsigned* __restrict__ amaxw){
  float s = fmaxf(__uint_as_float(*amaxw) / 6.0f, EPSF);
  int i = blockIdx.x*256 + threadIdx.x;          // 4.19M groups of 4
  int n = i >> 10, d = (i & 1023)*4;
  float4 v = *(const float4*)(w + (size_t)n*4096 + d);
  bf16x4 o;
  o[0] = (__bf16)qgrid(v.x, s); o[1] = (__bf16)qgrid(v.y, s);
  o[2] = (__bf16)qgrid(v.z, s); o[3] = (__bf16)qgrid(v.w, s);
  *(bf16x4*)(Bq + (size_t)n*4160 + d) = o;
}

// ---------------- quantize U -> Aq[:, 4096:4160]  grid 2048 ----------------
__global__ void k_qu(__bf16* __restrict__ Aq, const float* __restrict__ U,
                     const unsigned* __restrict__ amaxu){
  float s = fmaxf(__uint_as_float(*amaxu) / 6.0f, EPSF);
  int i = blockIdx.x*256 + threadIdx.x;
  int m = i >> 6, k = i & 63;
  Aq[(size_t)m*4160 + 4096 + k] = (__bf16)qgrid(U[i], s);
}

// ---------------- quantize V -> Vq[k][d] (LDS transpose)  grid 64 ----------------
__global__ void k_qv(__bf16* __restrict__ Vq, const float* __restrict__ V,
                     const unsigned* __restrict__ amaxv){
  __shared__ float Vt[64][65];
  float s = fmaxf(__uint_as_float(*amaxv)/6.0f, EPSF);
  int d0 = blockIdx.x * 64;
  int t = threadIdx.x;
  for (int i = 0; i < 16; i++){
    int idx = i*256 + t; int r = idx >> 6, c = idx & 63;
    Vt[r][c] = V[(size_t)(d0 + r)*64 + c];
  }
  __syncthreads();
  for (int i = 0; i < 16; i++){
    int idx = i*256 + t; int k = idx >> 6, dd = idx & 63;
    Vq[(size_t)k*4096 + d0 + dd] = (__bf16)qgrid(Vt[dd][k], s);
  }
}

// ---------------- residual: ker = U@KV via 2-split MFMA; amax or quantize  grid(128,32) ----------------
// x tile [64x128] staged through LDS with full-cacheline float4 loads issued BEFORE
// the MFMA block (overlap); tail reads from LDS. Same MFMA order, same qgrid math,
// same store addresses -> numerics identical to the scalar-read version.
__global__ __launch_bounds__(256) void k_res(
    const float* __restrict__ x, const __bf16* __restrict__ Uh, const __bf16* __restrict__ Ul,
    const __bf16* __restrict__ Kh, const __bf16* __restrict__ Kl,
    unsigned* __restrict__ amaxr, __bf16* __restrict__ Aq, int mode){
  __shared__ float xs[64][132];                 // +4 pad: 16B-aligned rows, 2-way banks max
  int m0 = blockIdx.x * 64, n0 = blockIdx.y * 128;
  int t = threadIdx.x;
  int lane = t & 63, wave = t >> 6;
  int kgrp = lane >> 4, lrow = lane & 15;
  // stage: 8 threads/row -> 128B full-line requests; rows t>>3 and t>>3+32
  {
    int rr = t >> 3, cc = (t & 7) * 4;
    #pragma unroll
    for (int j = 0; j < 2; j++){
      const float* gr = x + (size_t)(m0 + rr + j*32)*4096 + n0;
      #pragma unroll
      for (int i = 0; i < 4; i++)
        *(float4*)&xs[rr + j*32][cc + i*32] = *(const float4*)(gr + cc + i*32);
    }
  }
  int mrow = m0 + wave*16 + lrow;
  f32x4 acc[8] = {};
  #pragma unroll
  for (int ks = 0; ks < 2; ks++){
    size_t ao = (size_t)mrow*64 + ks*32 + kgrp*8;
    bf16x8 uh = *(const bf16x8*)(Uh + ao);
    bf16x8 ul = *(const bf16x8*)(Ul + ao);
    #pragma unroll
    for (int n = 0; n < 8; n++){
      size_t bo = (size_t)(n0 + n*16 + lrow)*64 + ks*32 + kgrp*8;
      bf16x8 kh = *(const bf16x8*)(Kh + bo);
      bf16x8 kl = *(const bf16x8*)(Kl + bo);
      acc[n] = __builtin_amdgcn_mfma_f32_16x16x32_bf16(uh, kh, acc[n],0,0,0);
      acc[n] = __builtin_amdgcn_mfma_f32_16x16x32_bf16(uh, kl, acc[n],0,0,0);
      acc[n] = __builtin_amdgcn_mfma_f32_16x16x32_bf16(ul, kh, acc[n],0,0,0);
    }
  }
  __syncthreads();                              // xs ready (staging overlapped MFMA)
  int rloc = wave*16 + kgrp*4;                  // local row of this lane's 4 outputs
  if (mode == 0){
    float mx = 0.f;
    #pragma unroll
    for (int n = 0; n < 8; n++){
      int c = n*16 + lrow;
      #pragma unroll
      for (int r = 0; r < 4; r++)
        mx = fmaxf(mx, fabsf(xs[rloc + r][c] - acc[n][r]));
    }
    for (int o = 32; o > 0; o >>= 1) mx = fmaxf(mx, __shfl_down(mx, o, 64));
    __shared__ float sm[4];
    if (lane == 0) sm[wave] = mx;
    __syncthreads();
    if (threadIdx.x == 0)
      atomicMax(amaxr, __float_as_uint(fmaxf(fmaxf(sm[0],sm[1]), fmaxf(sm[2],sm[3]))));
  } else {
    float s = fmaxf(__uint_as_float(*amaxr)/6.0f, EPSF);
    int mb = m0 + rloc;
    #pragma unroll
    for (int n = 0; n < 8; n++){
      int c = n*16 + lrow;
      #pragma unroll
      for (int r = 0; r < 4; r++)
        Aq[(size_t)(mb + r)*4160 + n0 + c] =
          (__bf16)qgrid(xs[rloc + r][c] - acc[n][r], s);
    }
  }
}

// ---------------- M1 += Vq @ Wq^T  (exact bf16 MFMA)  grid(64,8) ----------------
__global__ __launch_bounds__(256) void k_m1(
    float* __restrict__ M1g, const __bf16* __restrict__ Vq, const __bf16* __restrict__ Bq){
  int n0 = blockIdx.x * 64;
  int k0 = blockIdx.y * 512;
  int lane = threadIdx.x & 63, wave = threadIdx.x >> 6;
  int kgrp = lane >> 4, lrow = lane & 15;
  int nrow = n0 + wave*16 + lrow;
  f32x4 acc[4] = {};
  for (int kc = k0; kc < k0 + 512; kc += 32){
    bf16x8 fb = *(const bf16x8*)(Bq + (size_t)nrow*4160 + kc + kgrp*8);
    #pragma unroll
    for (int mt = 0; mt < 4; mt++){
      bf16x8 fa = *(const bf16x8*)(Vq + (size_t)(mt*16 + lrow)*4096 + kc + kgrp*8);
      acc[mt] = __builtin_amdgcn_mfma_f32_16x16x32_bf16(fa, fb, acc[mt],0,0,0);
    }
  }
  #pragma unroll
  for (int mt = 0; mt < 4; mt++)
    #pragma unroll
    for (int r = 0; r < 4; r++)
      atomicAdd(&M1g[(size_t)(mt*16 + kgrp*4 + r)*4096 + nrow], acc[mt][r]);
}

// ---------------- M2T: Bq[:, 4096:4160] = M1[k][n] * su*sv*S[k]/sr  grid 1024 ----------------
__global__ void k_m2t(__bf16* __restrict__ Bq, const float* __restrict__ M1g,
                      const float* __restrict__ S, const unsigned* __restrict__ scal){
  float su = fmaxf(__uint_as_float(scal[1])/6.0f, EPSF);
  float sv = fmaxf(__uint_as_float(scal[2])/6.0f, EPSF);
  float sr = fmaxf(__uint_as_float(scal[3])/6.0f, EPSF);
  int i = blockIdx.x*256 + threadIdx.x;
  int n = i >> 6, k = i & 63;
  float v = M1g[(size_t)k*4096 + n] * (su * sv * S[k] / sr);
  Bq[(size_t)n*4160 + 4096 + k] = (__bf16)v;
}

// ---------------- main bf16 MFMA GEMM: out = (A @ B^T)*sr*sw + bias ----------------
// 256x256 tile, BK=32, 512 threads (8 waves, 2Mx4N), 4-deep LDS ring (128 KiB).
// Counted s_waitcnt vmcnt(8) + builtin s_barrier, setprio around MFMA cluster,
// nontemporal epilogue stores. Verified best at ~237 us (R4/R7).
__global__ __launch_bounds__(512, 2)
void k_gemm(float* __restrict__ out, const __bf16* __restrict__ A,
            const __bf16* __restrict__ B, const float* __restrict__ bias,
            const unsigned* __restrict__ scal){
  __shared__ __align__(16) __bf16 As[4*8192];   // 4 ring slots x 128 packed rows x 64 el
  __shared__ __align__(16) __bf16 Bs[4*8192];
  const int m0 = blockIdx.y * 256, n0 = blockIdx.x * 256;
  const int tid = threadIdx.x;
  const int lane = tid & 63, wave = tid >> 6;
  const int wrow = wave >> 2, wcol = wave & 3;     // 2 x 4 wave grid
  const int kg = lane >> 4, lr = lane & 15;
  f32x4 acc[8][4] = {};

  auto STAGE = [&](int tt){
    __bf16* as = &As[(tt & 3) * 8192];
    __bf16* bs = &Bs[(tt & 3) * 8192];
    const int kt = tt * 32;
    #pragma unroll
    for (int q = 0; q < 2; q++){
      int idx = q * 512 + tid;                 // 1024 16B-slots per matrix
      int rp  = idx >> 3;                      // packed LDS row 0..127
      int sp  = (idx & 7) ^ (rp & 7);          // unswizzled slot
      int grow = rp * 2 + (sp >> 2);           // global tile row 0..255
      int gcol = (sp & 3) * 8;                 // global k element 0..24
      const __bf16* ga = A + (size_t)(m0 + grow) * KT + kt + gcol;
      const __bf16* gb = B + (size_t)(n0 + grow) * KT + kt + gcol;
      __bf16* la = as + (size_t)(idx & ~63) * 8;
      __bf16* lb = bs + (size_t)(idx & ~63) * 8;
      __builtin_amdgcn_global_load_lds((const __attribute__((address_space(1))) uint32_t*)ga,
                                       (__attribute__((address_space(3))) uint32_t*)la, 16, 0, 0);
      __builtin_amdgcn_global_load_lds((const __attribute__((address_space(1))) uint32_t*)gb,
                                       (__attribute__((address_space(3))) uint32_t*)lb, 16, 0, 0);
    }
  };

  auto BODY = [&](int t, bool stage){
    const __bf16* as = &As[(t & 3) * 8192];
    const __bf16* bs = &Bs[(t & 3) * 8192];
    bf16x8 fa[8], fb[4];
    #pragma unroll
    for (int mf = 0; mf < 8; mf++){
      int row = wrow*128 + mf*16 + lr;
      int rp  = row >> 1;
      int sl  = (((row & 1) << 2) | kg) ^ (rp & 7);
      fa[mf] = *(const bf16x8*)(as + (size_t)rp*64 + sl*8);
    }
    #pragma unroll
    for (int nf = 0; nf < 4; nf++){
      int row = wcol*64 + nf*16 + lr;
      int rp  = row >> 1;
      int sl  = (((row & 1) << 2) | kg) ^ (rp & 7);
      fb[nf] = *(const bf16x8*)(bs + (size_t)rp*64 + sl*8);
    }
    if (stage) STAGE(t + 3);                    // slot (t+3)&3: last read at iter t-1, safe
    __builtin_amdgcn_s_setprio(1);
    #pragma unroll
    for (int mf = 0; mf < 8; mf++)
      #pragma unroll
      for (int nf = 0; nf < 4; nf++)
        acc[mf][nf] = __builtin_amdgcn_mfma_f32_16x16x32_bf16(fa[mf], fb[nf], acc[mf][nf], 0, 0, 0);
    __builtin_amdgcn_s_setprio(0);
  };

  STAGE(0); STAGE(1); STAGE(2);                // prologue: 3 tiles (12 loads) in flight

  const int NT = KT / 32;                      // 130
  for (int t = 0; t < NT - 2; t++){
    asm volatile("s_waitcnt vmcnt(8)" ::: "memory");
    __builtin_amdgcn_s_barrier();
    BODY(t, t < NT - 3);
  }
  asm volatile("s_waitcnt vmcnt(4)" ::: "memory");
  __builtin_amdgcn_s_barrier();
  BODY(NT - 2, false);
  asm volatile("s_waitcnt vmcnt(0)" ::: "memory");
  __builtin_amdgcn_s_barrier();
  BODY(NT - 1, false);

  float sr = fmaxf(__uint_as_float(scal[3])/6.0f, EPSF);
  float sw = fmaxf(__uint_as_float(scal[0])/6.0f, EPSF);
  float srw = sr * sw;
  #pragma unroll
  for (int nf = 0; nf < 4; nf++){
    int n = n0 + wcol*64 + nf*16 + lr;
    float bv = bias[n];
    #pragma unroll
    for (int mf = 0; mf < 8; mf++){
      int mb = m0 + wrow*128 + mf*16 + 4*kg;
      #pragma unroll
      for (int r = 0; r < 4; r++)
        __builtin_nontemporal_store(acc[mf][nf][r]*srw + bv,
                                    &out[(size_t)(mb + r)*4096 + n]);
    }
  }
}

// ---------------- host side ----------------
extern "C" void kernel_launch(void* const* d_in, const int* in_sizes, int n_in,
                              void* d_out, int out_size, void* d_ws, size_t ws_size,
                              hipStream_t stream){
  const float* x    = (const float*)d_in[0];   // [8192, 4096]
  const float* wt   = (const float*)d_in[1];   // [4096, 4096]
  const float* bias = (const float*)d_in[2];   // [4096]
  const float* V0   = (const float*)d_in[3];   // [4096, 64]
  float* out = (float*)d_out;
  if (ws_size < WS_NEED) return;

  float* F = (float*)d_ws;
  unsigned* scal = (unsigned*)(F + oScal);
  __bf16* BFp = (__bf16*)((char*)d_ws + bfByte);
  __bf16* Vq  = BFp + oVq;
  __bf16* Aq  = BFp + oA;
  __bf16* Bq  = BFp + oB;
  __bf16* VcTh = BFp + oVcT,              *VcTm = VcTh + (size_t)64*4096, *VcTl = VcTm + (size_t)64*4096;
  __bf16* UTh  = BFp + oUT,               *UTm  = UTh + (size_t)64*8192,  *UTl  = UTm + (size_t)64*8192;
  __bf16* Uh   = BFp + oUhl,              *Ul   = Uh + (size_t)8192*64;
  __bf16* KVTh = BFp + oKVT,              *KVTl = KVTh + (size_t)4096*64;
  float *P = F+oP, *W = F+oW, *Gm = F+oG, *M1 = F+oM1, *Sv = F+oS,
        *Li = F+oLinv, *V = F+oV, *Ub = F+oU;

  dim3 b256(256);
  k_zero <<<dim3(2048), b256, 0, stream>>>(F, (int)nZero1);
  k_amax4<<<dim3(1024), b256, 0, stream>>>((const float4*)wt, 4194304, scal+0);
  k_qw   <<<dim3(16384), b256, 0, stream>>>(Bq, wt, scal+0);

  // ---- power iteration 1 ----
  k_prep_vct<<<dim3(64),  b256, 0, stream>>>(V0, VcTh, VcTm, VcTl);
  k_gv     <<<dim3(64,8), b256, 0, stream>>>(P, x, VcTh, VcTm, VcTl);
  k_gram   <<<dim3(64),   b256, 0, stream>>>(P, Gm);
  k_cholinv<<<dim3(1), dim3(64), 0, stream>>>(Gm, Li);
  k_applyq <<<dim3(128),  b256, 0, stream>>>(Ub, P, Li);
  k_prep_u <<<dim3(128),  b256, 0, stream>>>(Ub, Uh, Ul, UTh, UTm, UTl);
  k_gtu    <<<dim3(64,8), b256, 0, stream>>>(W, x, UTh, UTm, UTl);
  k_colnorm<<<dim3(64),   b256, 0, stream>>>(W, Sv);
  k_vnorm  <<<dim3(1024), b256, 0, stream>>>(V, W, Sv);

  // ---- power iteration 2 ----
  k_prep_vct<<<dim3(64),  b256, 0, stream>>>(V, VcTh, VcTm, VcTl);
  k_zero   <<<dim3(2048), b256, 0, stream>>>(F, (int)nZero2);      // P, W, Gram
  k_gv     <<<dim3(64,8), b256, 0, stream>>>(P, x, VcTh, VcTm, VcTl);
  k_gram   <<<dim3(64),   b256, 0, stream>>>(P, Gm);
  k_cholinv<<<dim3(1), dim3(64), 0, stream>>>(Gm, Li);
  k_applyq <<<dim3(128),  b256, 0, stream>>>(Ub, P, Li);
  k_prep_u <<<dim3(128),  b256, 0, stream>>>(Ub, Uh, Ul, UTh, UTm, UTl);
  k_gtu    <<<dim3(64,8), b256, 0, stream>>>(W, x, UTh, UTm, UTl);
  k_colnorm<<<dim3(64),   b256, 0, stream>>>(W, Sv);               // Sv = S
  k_vnkv   <<<dim3(1024), b256, 0, stream>>>(V, KVTh, KVTl, W, Sv, scal+2);

  // ---- quantize factors + residual ----
  k_amax4<<<dim3(1024), b256, 0, stream>>>((const float4*)Ub, 131072, scal+1);
  k_qu   <<<dim3(2048), b256, 0, stream>>>(Aq, Ub, scal+1);
  k_qv   <<<dim3(64),   b256, 0, stream>>>(Vq, V, scal+2);
  k_res  <<<dim3(128,32), b256, 0, stream>>>(x, Uh, Ul, KVTh, KVTl, scal+3, Aq, 0);
  k_res  <<<dim3(128,32), b256, 0, stream>>>(x, Uh, Ul, KVTh, KVTl, scal+3, Aq, 1);

  // ---- low-rank fold + main GEMM ----
  k_m1  <<<dim3(64,8), b256, 0, stream>>>(M1, Vq, Bq);
  k_m2t <<<dim3(1024), b256, 0, stream>>>(Bq, M1, Sv, scal);
  k_gemm<<<dim3(16,32), dim3(512), 0, stream>>>(out, Aq, Bq, bias, scal);
}

// Round 9
// 1367.720 us; speedup vs baseline: 1.2390x; 1.0500x over previous
//
#include <hip/hip_runtime.h>
#include <stdint.h>

#define EPSF 1e-8f
#define KT 4160

typedef float  f32x4  __attribute__((ext_vector_type(4)));
typedef __bf16 bf16x8 __attribute__((ext_vector_type(8)));
typedef __bf16 bf16x4 __attribute__((ext_vector_type(4)));

// ---------------- workspace layout ----------------
// fp32 region (element offsets)
constexpr size_t oP    = 0;                     // P   [8192*64]
constexpr size_t oW    = oP  + 8192*64;         // W   [4096*64]
constexpr size_t oG    = oW  + 4096*64;         // Gram[64*64]
constexpr size_t oM1   = oG  + 64*64;           // M1  [64*4096]
constexpr size_t oScal = oM1 + 64*4096;         // 4 u32: amax_w, amax_u, amax_v, amax_r
constexpr size_t nZero1= oScal + 4;             // initial zero: P,W,G,M1,scal
constexpr size_t nZero2= oG + 64*64;            // iter-2 zero: P,W,G
constexpr size_t oS    = nZero1;                // 64
constexpr size_t oLinv = oS + 64;               // 64*64
constexpr size_t oV    = oLinv + 64*64;         // V  [4096*64] (unused; layout kept)
constexpr size_t oU    = oV + 4096*64;          // Ub [8192*64]
constexpr size_t endF32= oU + 8192*64;
constexpr size_t bfByte= ((endF32*4 + 255)/256)*256;
// bf16 region (element offsets)
constexpr size_t oVq   = 0;                     // Vq [64*4096]
constexpr size_t oA    = oVq + 64*4096;         // A = [Rq | Uq]  [8192*4160]
constexpr size_t oB    = oA + (size_t)8192*4160;// B = [Wq | M2T] [4096*4160]
constexpr size_t oVcT  = oB + (size_t)4096*4160;// VcT h/m/l 3x[64*4096]
constexpr size_t oUT   = oVcT + 3*(size_t)64*4096;   // UT h/m/l 3x[64*8192]
constexpr size_t oUhl  = oUT + 3*(size_t)64*8192;    // U h/l 2x[8192*64]
constexpr size_t oKVT  = oUhl + 2*(size_t)8192*64;   // KVT h/l 2x[4096*64]
constexpr size_t endBF = oKVT + 2*(size_t)4096*64;
constexpr size_t WS_NEED = bfByte + endBF*2;

// ---------------- fp4 e2m1 helpers ----------------
__device__ __forceinline__ float qlevel(float a){
  if (a <= 0.25f) return 0.0f;
  if (a <= 0.75f) return 0.5f;
  if (a <= 1.25f) return 1.0f;
  if (a <= 1.75f) return 1.5f;
  if (a <= 2.5f)  return 2.0f;
  if (a <= 3.5f)  return 3.0f;
  if (a <= 5.0f)  return 4.0f;
  return 6.0f;
}
__device__ __forceinline__ float qgrid(float v, float s){
  float y = v / s;
  float l = qlevel(fabsf(y));
  return y < 0.0f ? -l : l;
}

// ---------------- utility ----------------
__global__ void k_zero(float* p, int n){
  for (int i = blockIdx.x*blockDim.x + threadIdx.x; i < n; i += gridDim.x*blockDim.x)
    p[i] = 0.0f;
}

__global__ void k_amax4(const float4* __restrict__ x, int n4, unsigned* __restrict__ out){
  float m = 0.f;
  for (int i = blockIdx.x*blockDim.x + threadIdx.x; i < n4; i += gridDim.x*blockDim.x){
    float4 v = x[i];
    m = fmaxf(m, fmaxf(fmaxf(fabsf(v.x), fabsf(v.y)), fmaxf(fabsf(v.z), fabsf(v.w))));
  }
  for (int o = 32; o > 0; o >>= 1) m = fmaxf(m, __shfl_down(m, o, 64));
  __shared__ float sm[4];
  int lane = threadIdx.x & 63, w = threadIdx.x >> 6;
  if (lane == 0) sm[w] = m;
  __syncthreads();
  if (threadIdx.x == 0)
    atomicMax(out, __float_as_uint(fmaxf(fmaxf(sm[0],sm[1]), fmaxf(sm[2],sm[3]))));
}

// ---------------- P += x @ Vc  via 3-word-split bf16 MFMA  grid(64,8) ----------------
__global__ __launch_bounds__(256) void k_gv(
    float* __restrict__ P, const float* __restrict__ x,
    const __bf16* __restrict__ Bh, const __bf16* __restrict__ Bm, const __bf16* __restrict__ Bl){
  int m0 = blockIdx.x * 128;
  int d0 = blockIdx.y * 512;
  int lane = threadIdx.x & 63, wave = threadIdx.x >> 6;
  int kgrp = lane >> 4, lrow = lane & 15;
  f32x4 acc[2][4] = {};
  for (int dc = d0; dc < d0 + 512; dc += 32){
    bf16x8 ah[2], am[2], al[2];
    #pragma unroll
    for (int f = 0; f < 2; f++){
      const float* g = x + (size_t)(m0 + wave*32 + f*16 + lrow)*4096 + dc + kgrp*8;
      float4 a = *(const float4*)g;
      float4 b = *(const float4*)(g + 4);
      float v[8] = {a.x,a.y,a.z,a.w,b.x,b.y,b.z,b.w};
      #pragma unroll
      for (int j = 0; j < 8; j++){
        __bf16 h = (__bf16)v[j];
        float r1 = v[j] - (float)h;
        __bf16 md = (__bf16)r1;
        float r2 = r1 - (float)md;
        ah[f][j] = h; am[f][j] = md; al[f][j] = (__bf16)r2;
      }
    }
    #pragma unroll
    for (int n = 0; n < 4; n++){
      size_t bo = (size_t)(n*16 + lrow)*4096 + dc + kgrp*8;
      bf16x8 bh = *(const bf16x8*)(Bh + bo);
      bf16x8 bm = *(const bf16x8*)(Bm + bo);
      bf16x8 bl = *(const bf16x8*)(Bl + bo);
      #pragma unroll
      for (int f = 0; f < 2; f++){
        acc[f][n] = __builtin_amdgcn_mfma_f32_16x16x32_bf16(ah[f], bh, acc[f][n],0,0,0);
        acc[f][n] = __builtin_amdgcn_mfma_f32_16x16x32_bf16(ah[f], bm, acc[f][n],0,0,0);
        acc[f][n] = __builtin_amdgcn_mfma_f32_16x16x32_bf16(am[f], bh, acc[f][n],0,0,0);
        acc[f][n] = __builtin_amdgcn_mfma_f32_16x16x32_bf16(ah[f], bl, acc[f][n],0,0,0);
        acc[f][n] = __builtin_amdgcn_mfma_f32_16x16x32_bf16(al[f], bh, acc[f][n],0,0,0);
        acc[f][n] = __builtin_amdgcn_mfma_f32_16x16x32_bf16(am[f], bm, acc[f][n],0,0,0);
      }
    }
  }
  #pragma unroll
  for (int f = 0; f < 2; f++)
    #pragma unroll
    for (int n = 0; n < 4; n++)
      #pragma unroll
      for (int r = 0; r < 4; r++)
        atomicAdd(&P[(size_t)(m0 + wave*32 + f*16 + kgrp*4 + r)*64 + n*16 + lrow], acc[f][n][r]);
}

// ---------------- W += x^T @ U  (LDS-transposed x, coalesced loads)  grid(64,8) ----------------
__global__ __launch_bounds__(256) void k_gtu(
    float* __restrict__ W, const float* __restrict__ x,
    const __bf16* __restrict__ Bh, const __bf16* __restrict__ Bm, const __bf16* __restrict__ Bl){
  __shared__ float xs[64][65];
  int d0 = blockIdx.x * 64;
  int m0 = blockIdx.y * 1024;
  int t = threadIdx.x;
  int lane = t & 63, wave = t >> 6;
  int kgrp = lane >> 4, lrow = lane & 15;
  int dloc = wave*16 + lrow;
  f32x4 acc[4] = {};
  int r0 = t >> 2, c0 = (t & 3) * 16;
  for (int mc64 = m0; mc64 < m0 + 1024; mc64 += 64){
    __syncthreads();
    const float* gr = x + (size_t)(mc64 + r0)*4096 + d0 + c0;
    #pragma unroll
    for (int i = 0; i < 4; i++)
      *(float4*)&xs[r0][c0 + 4*i] = *(const float4*)(gr + 4*i);
    __syncthreads();
    #pragma unroll
    for (int half = 0; half < 2; half++){
      int mc = mc64 + half*32;
      bf16x8 ah, am, al;
      int kb = half*32 + kgrp*8;
      #pragma unroll
      for (int j = 0; j < 8; j++){
        float v = xs[kb + j][dloc];
        __bf16 h = (__bf16)v;
        float r1 = v - (float)h;
        __bf16 md = (__bf16)r1;
        float r2 = r1 - (float)md;
        ah[j] = h; am[j] = md; al[j] = (__bf16)r2;
      }
      #pragma unroll
      for (int n = 0; n < 4; n++){
        size_t bo = (size_t)(n*16 + lrow)*8192 + mc + kgrp*8;
        bf16x8 bh = *(const bf16x8*)(Bh + bo);
        bf16x8 bm = *(const bf16x8*)(Bm + bo);
        bf16x8 bl = *(const bf16x8*)(Bl + bo);
        acc[n] = __builtin_amdgcn_mfma_f32_16x16x32_bf16(ah, bh, acc[n],0,0,0);
        acc[n] = __builtin_amdgcn_mfma_f32_16x16x32_bf16(ah, bm, acc[n],0,0,0);
        acc[n] = __builtin_amdgcn_mfma_f32_16x16x32_bf16(am, bh, acc[n],0,0,0);
        acc[n] = __builtin_amdgcn_mfma_f32_16x16x32_bf16(ah, bl, acc[n],0,0,0);
        acc[n] = __builtin_amdgcn_mfma_f32_16x16x32_bf16(al, bh, acc[n],0,0,0);
        acc[n] = __builtin_amdgcn_mfma_f32_16x16x32_bf16(am, bm, acc[n],0,0,0);
      }
    }
  }
  #pragma unroll
  for (int n = 0; n < 4; n++)
    #pragma unroll
    for (int r = 0; r < 4; r++)
      atomicAdd(&W[(size_t)(d0 + wave*16 + kgrp*4 + r)*64 + n*16 + lrow], acc[n][r]);
}

// ---------------- Gram += Pchunk^T Pchunk   grid 64 ----------------
__global__ void k_gram(const float* __restrict__ P, float* __restrict__ Gram){
  __shared__ float Pt[128][65];
  int m0 = blockIdx.x * 128;
  int t = threadIdx.x;
  for (int i = 0; i < 32; i++){
    int idx = i*256 + t; int r = idx >> 6, c = idx & 63;
    Pt[r][c] = P[(size_t)(m0+r)*64 + c];
  }
  __syncthreads();
  int ti = t >> 4, tj = t & 15;
  float acc[4][4] = {};
  for (int r = 0; r < 128; r++){
    float a[4], b[4];
    #pragma unroll
    for (int q = 0; q < 4; q++) a[q] = Pt[r][ti*4+q];
    #pragma unroll
    for (int q = 0; q < 4; q++) b[q] = Pt[r][tj*4+q];
    #pragma unroll
    for (int xx = 0; xx < 4; xx++)
      #pragma unroll
      for (int y = 0; y < 4; y++) acc[xx][y] += a[xx]*b[y];
  }
  for (int xx = 0; xx < 4; xx++)
    for (int y = 0; y < 4; y++)
      atomicAdd(&Gram[(ti*4+xx)*64 + tj*4+y], acc[xx][y]);
}

// ---------------- fp64 Cholesky of Gram + lower-tri inverse  (256 threads) ----------------
// Factorization row-updates are independent single-element updates -> 4-way j-split
// by residue is numerically IDENTICAL. Back-substitution (ordered sum) runs on
// threads 0..63 exactly as the 64-thread version -> bitwise-identical Linv.
__global__ void k_cholinv(const float* __restrict__ Gram, float* __restrict__ Linv){
  __shared__ double A[64][64];
  __shared__ double Li[64][64];
  int t = threadIdx.x;            // 0..255
  int row = t & 63, q = t >> 6;   // 4 quarters
  for (int i = 0; i < 16; i++){
    int idx = i*256 + t; int r = idx >> 6, c = idx & 63;
    A[r][c] = (double)Gram[r*64 + c];
    Li[r][c] = 0.0;
  }
  __syncthreads();
  for (int k = 0; k < 64; k++){
    if (t == k) A[k][k] = sqrt(A[k][k]);
    __syncthreads();
    if (q == 0 && row > k) A[row][k] /= A[k][k];
    __syncthreads();
    if (row > k){
      double aik = A[row][k];
      for (int j = k+1+q; j <= row; j += 4) A[row][j] -= aik * A[j][k];
    }
    __syncthreads();
  }
  if (q == 0){
    for (int i = row; i < 64; i++){
      double s = (i == row) ? 1.0 : 0.0;
      for (int p = row; p < i; p++) s -= A[i][p] * Li[p][row];
      Li[i][row] = s / A[i][i];
    }
  }
  __syncthreads();
  for (int i = 0; i < 16; i++){
    int idx = i*256 + t; int r = idx >> 6, c = idx & 63;
    Linv[r*64 + c] = (float)Li[r][c];
  }
}

// ---------------- U = P @ Linv^T   grid 128 ----------------
__global__ void k_applyq(float* __restrict__ U, const float* __restrict__ P,
                         const float* __restrict__ Linv){
  __shared__ float Pt[64][65];
  __shared__ float Lt[64][65];
  int m0 = blockIdx.x * 64;
  int t = threadIdx.x;
  for (int i = 0; i < 16; i++){
    int idx = i*256 + t; int r = idx >> 6, c = idx & 63;
    Pt[r][c] = P[(size_t)(m0+r)*64 + c];
    Lt[r][c] = Linv[r*64 + c];
  }
  __syncthreads();
  int tm = t >> 4, tj = t & 15;
  float acc[4][4] = {};
  for (int i = 0; i < 64; i++){
    float p[4], lv[4];
    #pragma unroll
    for (int a = 0; a < 4; a++) p[a]  = Pt[tm*4+a][i];
    #pragma unroll
    for (int b = 0; b < 4; b++) lv[b] = Lt[tj*4+b][i];
    #pragma unroll
    for (int a = 0; a < 4; a++)
      #pragma unroll
      for (int b = 0; b < 4; b++) acc[a][b] += p[a]*lv[b];
  }
  for (int a = 0; a < 4; a++)
    for (int b = 0; b < 4; b++)
      U[(size_t)(m0+tm*4+a)*64 + tj*4+b] = acc[a][b];
}

// ---------------- column norms of W[4096,64]  grid 64 ----------------
__global__ void k_colnorm(const float* __restrict__ W, float* __restrict__ cn){
  int k = blockIdx.x;
  float s = 0.f;
  for (int d = threadIdx.x; d < 4096; d += 256){
    float v = W[(size_t)d*64 + k];
    s += v*v;
  }
  for (int o = 32; o > 0; o >>= 1) s += __shfl_down(s, o, 64);
  __shared__ float sm[4];
  int lane = threadIdx.x & 63, w = threadIdx.x >> 6;
  if (lane == 0) sm[w] = s;
  __syncthreads();
  if (threadIdx.x == 0) cn[k] = sqrtf(sm[0]+sm[1]+sm[2]+sm[3]);
}

// KVT[d][k] = S*Vn (bf16 h/l); amax_v of Vn = W/(S+EPS)   grid 1024  (V not materialized)
__global__ void k_kv(__bf16* __restrict__ Kh, __bf16* __restrict__ Kl,
                     const float* __restrict__ W, const float* __restrict__ S,
                     unsigned* __restrict__ amaxv){
  int i = blockIdx.x*256 + threadIdx.x;
  int k = i & 63, d = i >> 6;
  float s = S[k];
  float vn = W[i] / (s + EPSF);
  float kv = s * vn;
  __bf16 h = (__bf16)kv;
  Kh[(size_t)d*64 + k] = h;
  Kl[(size_t)d*64 + k] = (__bf16)(kv - (float)h);
  float m = fabsf(vn);
  for (int o = 32; o > 0; o >>= 1) m = fmaxf(m, __shfl_down(m, o, 64));
  __shared__ float sm[4];
  int lane = threadIdx.x & 63, w = threadIdx.x >> 6;
  if (lane == 0) sm[w] = m;
  __syncthreads();
  if (threadIdx.x == 0)
    atomicMax(amaxv, __float_as_uint(fmaxf(fmaxf(sm[0],sm[1]), fmaxf(sm[2],sm[3]))));
}

// ---------------- transpose+3-split prep: Vc[4096,64] -> VcT h/m/l [64,4096]  grid 64 ----------------
__global__ void k_prep_vct(const float* __restrict__ Vc, __bf16* __restrict__ Th,
                           __bf16* __restrict__ Tm, __bf16* __restrict__ Tl){
  __shared__ float Vt[64][65];
  int d0 = blockIdx.x * 64;
  int t = threadIdx.x;
  for (int i = 0; i < 16; i++){
    int idx = i*256 + t; int r = idx >> 6, c = idx & 63;
    Vt[r][c] = Vc[(size_t)(d0 + r)*64 + c];
  }
  __syncthreads();
  for (int i = 0; i < 16; i++){
    int idx = i*256 + t; int k = idx >> 6, dd = idx & 63;
    float v = Vt[dd][k];
    __bf16 h = (__bf16)v;
    float r1 = v - (float)h;
    __bf16 md = (__bf16)r1;
    float r2 = r1 - (float)md;
    size_t o = (size_t)k*4096 + d0 + dd;
    Th[o] = h; Tm[o] = md; Tl[o] = (__bf16)r2;
  }
}

// normalized variant: V = W/(cn+EPS) computed on the fly (V never materialized)  grid 64
__global__ void k_prep_vctn(const float* __restrict__ W, const float* __restrict__ cn,
                            __bf16* __restrict__ Th, __bf16* __restrict__ Tm,
                            __bf16* __restrict__ Tl){
  __shared__ float Vt[64][65];
  __shared__ float cs[64];
  int d0 = blockIdx.x * 64;
  int t = threadIdx.x;
  if (t < 64) cs[t] = cn[t];
  __syncthreads();
  for (int i = 0; i < 16; i++){
    int idx = i*256 + t; int r = idx >> 6, c = idx & 63;
    Vt[r][c] = W[(size_t)(d0 + r)*64 + c] / (cs[c] + EPSF);
  }
  __syncthreads();
  for (int i = 0; i < 16; i++){
    int idx = i*256 + t; int k = idx >> 6, dd = idx & 63;
    float v = Vt[dd][k];
    __bf16 h = (__bf16)v;
    float r1 = v - (float)h;
    __bf16 md = (__bf16)r1;
    float r2 = r1 - (float)md;
    size_t o = (size_t)k*4096 + d0 + dd;
    Th[o] = h; Tm[o] = md; Tl[o] = (__bf16)r2;
  }
}

// prep U: Ub[8192,64] -> U h/l [8192,64] + UT h/m/l [64,8192]   grid 128
__global__ void k_prep_u(const float* __restrict__ Ub, __bf16* __restrict__ Uh, __bf16* __restrict__ Ul,
                         __bf16* __restrict__ Th, __bf16* __restrict__ Tm, __bf16* __restrict__ Tl){
  __shared__ float Ut[64][65];
  int m0 = blockIdx.x * 64;
  int t = threadIdx.x;
  for (int i = 0; i < 16; i++){
    int idx = i*256 + t; int r = idx >> 6, c = idx & 63;
    float v = Ub[(size_t)(m0 + r)*64 + c];
    Ut[r][c] = v;
    __bf16 h = (__bf16)v;
    Uh[(size_t)(m0+r)*64 + c] = h;
    Ul[(size_t)(m0+r)*64 + c] = (__bf16)(v - (float)h);
  }
  __syncthreads();
  for (int i = 0; i < 16; i++){
    int idx = i*256 + t; int k = idx >> 6, mm = idx & 63;
    float v = Ut[mm][k];
    __bf16 h = (__bf16)v;
    float r1 = v - (float)h;
    __bf16 md = (__bf16)r1;
    float r2 = r1 - (float)md;
    size_t o = (size_t)k*8192 + m0 + mm;
    Th[o] = h; Tm[o] = md; Tl[o] = (__bf16)r2;
  }
}

// ---------------- quantize weight -> Bq[:, :4096]  (float4)  grid 16384 ----------------
__global__ void k_qw(__bf16* __restrict__ Bq, const float* __restrict__ w,
                     const unsigned* __restrict__ amaxw){
  float s = fmaxf(__uint_as_float(*amaxw) / 6.0f, EPSF);
  int i = blockIdx.x*256 + threadIdx.x;          // 4.19M groups of 4
  int n = i >> 10, d = (i & 1023)*4;
  float4 v = *(const float4*)(w + (size_t)n*4096 + d);
  bf16x4 o;
  o[0] = (__bf16)qgrid(v.x, s); o[1] = (__bf16)qgrid(v.y, s);
  o[2] = (__bf16)qgrid(v.z, s); o[3] = (__bf16)qgrid(v.w, s);
  *(bf16x4*)(Bq + (size_t)n*4160 + d) = o;
}

// ---------------- quantize U -> Aq[:, 4096:4160]  grid 2048 ----------------
__global__ void k_qu(__bf16* __restrict__ Aq, const float* __restrict__ U,
                     const unsigned* __restrict__ amaxu){
  float s = fmaxf(__uint_as_float(*amaxu) / 6.0f, EPSF);
  int i = blockIdx.x*256 + threadIdx.x;
  int m = i >> 6, k = i & 63;
  Aq[(size_t)m*4160 + 4096 + k] = (__bf16)qgrid(U[i], s);
}

// ---------------- quantize V -> Vq[k][d] (LDS transpose; V = W/(S+EPS) on the fly)  grid 64 ----------------
__global__ void k_qv(__bf16* __restrict__ Vq, const float* __restrict__ W,
                     const float* __restrict__ S, const unsigned* __restrict__ amaxv){
  __shared__ float Vt[64][65];
  __shared__ float cs[64];
  float s = fmaxf(__uint_as_float(*amaxv)/6.0f, EPSF);
  int d0 = blockIdx.x * 64;
  int t = threadIdx.x;
  if (t < 64) cs[t] = S[t];
  __syncthreads();
  for (int i = 0; i < 16; i++){
    int idx = i*256 + t; int r = idx >> 6, c = idx & 63;
    Vt[r][c] = W[(size_t)(d0 + r)*64 + c] / (cs[c] + EPSF);
  }
  __syncthreads();
  for (int i = 0; i < 16; i++){
    int idx = i*256 + t; int k = idx >> 6, dd = idx & 63;
    Vq[(size_t)k*4096 + d0 + dd] = (__bf16)qgrid(Vt[dd][k], s);
  }
}

// ---------------- residual: ker = U@KV via 2-split MFMA; amax or quantize  grid(128,32) ----------------
__global__ __launch_bounds__(256) void k_res(
    const float* __restrict__ x, const __bf16* __restrict__ Uh, const __bf16* __restrict__ Ul,
    const __bf16* __restrict__ Kh, const __bf16* __restrict__ Kl,
    unsigned* __restrict__ amaxr, __bf16* __restrict__ Aq, int mode){
  __shared__ float xs[64][132];
  int m0 = blockIdx.x * 64, n0 = blockIdx.y * 128;
  int t = threadIdx.x;
  int lane = t & 63, wave = t >> 6;
  int kgrp = lane >> 4, lrow = lane & 15;
  {
    int rr = t >> 3, cc = (t & 7) * 4;
    #pragma unroll
    for (int j = 0; j < 2; j++){
      const float* gr = x + (size_t)(m0 + rr + j*32)*4096 + n0;
      #pragma unroll
      for (int i = 0; i < 4; i++)
        *(float4*)&xs[rr + j*32][cc + i*32] = *(const float4*)(gr + cc + i*32);
    }
  }
  int mrow = m0 + wave*16 + lrow;
  f32x4 acc[8] = {};
  #pragma unroll
  for (int ks = 0; ks < 2; ks++){
    size_t ao = (size_t)mrow*64 + ks*32 + kgrp*8;
    bf16x8 uh = *(const bf16x8*)(Uh + ao);
    bf16x8 ul = *(const bf16x8*)(Ul + ao);
    #pragma unroll
    for (int n = 0; n < 8; n++){
      size_t bo = (size_t)(n0 + n*16 + lrow)*64 + ks*32 + kgrp*8;
      bf16x8 kh = *(const bf16x8*)(Kh + bo);
      bf16x8 kl = *(const bf16x8*)(Kl + bo);
      acc[n] = __builtin_amdgcn_mfma_f32_16x16x32_bf16(uh, kh, acc[n],0,0,0);
      acc[n] = __builtin_amdgcn_mfma_f32_16x16x32_bf16(uh, kl, acc[n],0,0,0);
      acc[n] = __builtin_amdgcn_mfma_f32_16x16x32_bf16(ul, kh, acc[n],0,0,0);
    }
  }
  __syncthreads();
  int rloc = wave*16 + kgrp*4;
  if (mode == 0){
    float mx = 0.f;
    #pragma unroll
    for (int n = 0; n < 8; n++){
      int c = n*16 + lrow;
      #pragma unroll
      for (int r = 0; r < 4; r++)
        mx = fmaxf(mx, fabsf(xs[rloc + r][c] - acc[n][r]));
    }
    for (int o = 32; o > 0; o >>= 1) mx = fmaxf(mx, __shfl_down(mx, o, 64));
    __shared__ float sm[4];
    if (lane == 0) sm[wave] = mx;
    __syncthreads();
    if (threadIdx.x == 0)
      atomicMax(amaxr, __float_as_uint(fmaxf(fmaxf(sm[0],sm[1]), fmaxf(sm[2],sm[3]))));
  } else {
    float s = fmaxf(__uint_as_float(*amaxr)/6.0f, EPSF);
    int mb = m0 + rloc;
    #pragma unroll
    for (int n = 0; n < 8; n++){
      int c = n*16 + lrow;
      #pragma unroll
      for (int r = 0; r < 4; r++)
        Aq[(size_t)(mb + r)*4160 + n0 + c] =
          (__bf16)qgrid(xs[rloc + r][c] - acc[n][r], s);
    }
  }
}

// ---------------- M1 += Vq @ Wq^T  (exact bf16 MFMA)  grid(64,8) ----------------
__global__ __launch_bounds__(256) void k_m1(
    float* __restrict__ M1g, const __bf16* __restrict__ Vq, const __bf16* __restrict__ Bq){
  int n0 = blockIdx.x * 64;
  int k0 = blockIdx.y * 512;
  int lane = threadIdx.x & 63, wave = threadIdx.x >> 6;
  int kgrp = lane >> 4, lrow = lane & 15;
  int nrow = n0 + wave*16 + lrow;
  f32x4 acc[4] = {};
  for (int kc = k0; kc < k0 + 512; kc += 32){
    bf16x8 fb = *(const bf16x8*)(Bq + (size_t)nrow*4160 + kc + kgrp*8);
    #pragma unroll
    for (int mt = 0; mt < 4; mt++){
      bf16x8 fa = *(const bf16x8*)(Vq + (size_t)(mt*16 + lrow)*4096 + kc + kgrp*8);
      acc[mt] = __builtin_amdgcn_mfma_f32_16x16x32_bf16(fa, fb, acc[mt],0,0,0);
    }
  }
  #pragma unroll
  for (int mt = 0; mt < 4; mt++)
    #pragma unroll
    for (int r = 0; r < 4; r++)
      atomicAdd(&M1g[(size_t)(mt*16 + kgrp*4 + r)*4096 + nrow], acc[mt][r]);
}

// ---------------- M2T: Bq[:, 4096:4160] = M1[k][n] * su*sv*S[k]/sr  grid 1024 ----------------
__global__ void k_m2t(__bf16* __restrict__ Bq, const float* __restrict__ M1g,
                      const float* __restrict__ S, const unsigned* __restrict__ scal){
  float su = fmaxf(__uint_as_float(scal[1])/6.0f, EPSF);
  float sv = fmaxf(__uint_as_float(scal[2])/6.0f, EPSF);
  float sr = fmaxf(__uint_as_float(scal[3])/6.0f, EPSF);
  int i = blockIdx.x*256 + threadIdx.x;
  int n = i >> 6, k = i & 63;
  float v = M1g[(size_t)k*4096 + n] * (su * sv * S[k] / sr);
  Bq[(size_t)n*4160 + 4096 + k] = (__bf16)v;
}

// ---------------- main bf16 MFMA GEMM: out = (A @ B^T)*sr*sw + bias ----------------
// 256x256 tile, BK=32, 512 threads (8 waves, 2Mx4N), 4-deep LDS ring (128 KiB).
// Counted s_waitcnt vmcnt(8) + builtin s_barrier, setprio around MFMA cluster,
// nontemporal epilogue stores. Verified best at ~237 us (R4/R7/R8).
__global__ __launch_bounds__(512, 2)
void k_gemm(float* __restrict__ out, const __bf16* __restrict__ A,
            const __bf16* __restrict__ B, const float* __restrict__ bias,
            const unsigned* __restrict__ scal){
  __shared__ __align__(16) __bf16 As[4*8192];
  __shared__ __align__(16) __bf16 Bs[4*8192];
  const int m0 = blockIdx.y * 256, n0 = blockIdx.x * 256;
  const int tid = threadIdx.x;
  const int lane = tid & 63, wave = tid >> 6;
  const int wrow = wave >> 2, wcol = wave & 3;
  const int kg = lane >> 4, lr = lane & 15;
  f32x4 acc[8][4] = {};

  auto STAGE = [&](int tt){
    __bf16* as = &As[(tt & 3) * 8192];
    __bf16* bs = &Bs[(tt & 3) * 8192];
    const int kt = tt * 32;
    #pragma unroll
    for (int q = 0; q < 2; q++){
      int idx = q * 512 + tid;
      int rp  = idx >> 3;
      int sp  = (idx & 7) ^ (rp & 7);
      int grow = rp * 2 + (sp >> 2);
      int gcol = (sp & 3) * 8;
      const __bf16* ga = A + (size_t)(m0 + grow) * KT + kt + gcol;
      const __bf16* gb = B + (size_t)(n0 + grow) * KT + kt + gcol;
      __bf16* la = as + (size_t)(idx & ~63) * 8;
      __bf16* lb = bs + (size_t)(idx & ~63) * 8;
      __builtin_amdgcn_global_load_lds((const __attribute__((address_space(1))) uint32_t*)ga,
                                       (__attribute__((address_space(3))) uint32_t*)la, 16, 0, 0);
      __builtin_amdgcn_global_load_lds((const __attribute__((address_space(1))) uint32_t*)gb,
                                       (__attribute__((address_space(3))) uint32_t*)lb, 16, 0, 0);
    }
  };

  auto BODY = [&](int t, bool stage){
    const __bf16* as = &As[(t & 3) * 8192];
    const __bf16* bs = &Bs[(t & 3) * 8192];
    bf16x8 fa[8], fb[4];
    #pragma unroll
    for (int mf = 0; mf < 8; mf++){
      int row = wrow*128 + mf*16 + lr;
      int rp  = row >> 1;
      int sl  = (((row & 1) << 2) | kg) ^ (rp & 7);
      fa[mf] = *(const bf16x8*)(as + (size_t)rp*64 + sl*8);
    }
    #pragma unroll
    for (int nf = 0; nf < 4; nf++){
      int row = wcol*64 + nf*16 + lr;
      int rp  = row >> 1;
      int sl  = (((row & 1) << 2) | kg) ^ (rp & 7);
      fb[nf] = *(const bf16x8*)(bs + (size_t)rp*64 + sl*8);
    }
    if (stage) STAGE(t + 3);
    __builtin_amdgcn_s_setprio(1);
    #pragma unroll
    for (int mf = 0; mf < 8; mf++)
      #pragma unroll
      for (int nf = 0; nf < 4; nf++)
        acc[mf][nf] = __builtin_amdgcn_mfma_f32_16x16x32_bf16(fa[mf], fb[nf], acc[mf][nf], 0, 0, 0);
    __builtin_amdgcn_s_setprio(0);
  };

  STAGE(0); STAGE(1); STAGE(2);

  const int NT = KT / 32;                      // 130
  for (int t = 0; t < NT - 2; t++){
    asm volatile("s_waitcnt vmcnt(8)" ::: "memory");
    __builtin_amdgcn_s_barrier();
    BODY(t, t < NT - 3);
  }
  asm volatile("s_waitcnt vmcnt(4)" ::: "memory");
  __builtin_amdgcn_s_barrier();
  BODY(NT - 2, false);
  asm volatile("s_waitcnt vmcnt(0)" ::: "memory");
  __builtin_amdgcn_s_barrier();
  BODY(NT - 1, false);

  float sr = fmaxf(__uint_as_float(scal[3])/6.0f, EPSF);
  float sw = fmaxf(__uint_as_float(scal[0])/6.0f, EPSF);
  float srw = sr * sw;
  #pragma unroll
  for (int nf = 0; nf < 4; nf++){
    int n = n0 + wcol*64 + nf*16 + lr;
    float bv = bias[n];
    #pragma unroll
    for (int mf = 0; mf < 8; mf++){
      int mb = m0 + wrow*128 + mf*16 + 4*kg;
      #pragma unroll
      for (int r = 0; r < 4; r++)
        __builtin_nontemporal_store(acc[mf][nf][r]*srw + bv,
                                    &out[(size_t)(mb + r)*4096 + n]);
    }
  }
}

// ---------------- host side ----------------
extern "C" void kernel_launch(void* const* d_in, const int* in_sizes, int n_in,
                              void* d_out, int out_size, void* d_ws, size_t ws_size,
                              hipStream_t stream){
  const float* x    = (const float*)d_in[0];   // [8192, 4096]
  const float* wt   = (const float*)d_in[1];   // [4096, 4096]
  const float* bias = (const float*)d_in[2];   // [4096]
  const float* V0   = (const float*)d_in[3];   // [4096, 64]
  float* out = (float*)d_out;
  if (ws_size < WS_NEED) return;

  float* F = (float*)d_ws;
  unsigned* scal = (unsigned*)(F + oScal);
  __bf16* BFp = (__bf16*)((char*)d_ws + bfByte);
  __bf16* Vq  = BFp + oVq;
  __bf16* Aq  = BFp + oA;
  __bf16* Bq  = BFp + oB;
  __bf16* VcTh = BFp + oVcT,              *VcTm = VcTh + (size_t)64*4096, *VcTl = VcTm + (size_t)64*4096;
  __bf16* UTh  = BFp + oUT,               *UTm  = UTh + (size_t)64*8192,  *UTl  = UTm + (size_t)64*8192;
  __bf16* Uh   = BFp + oUhl,              *Ul   = Uh + (size_t)8192*64;
  __bf16* KVTh = BFp + oKVT,              *KVTl = KVTh + (size_t)4096*64;
  float *P = F+oP, *W = F+oW, *Gm = F+oG, *M1 = F+oM1, *Sv = F+oS,
        *Li = F+oLinv, *Ub = F+oU;

  dim3 b256(256);
  k_zero <<<dim3(2048), b256, 0, stream>>>(F, (int)nZero1);
  k_amax4<<<dim3(1024), b256, 0, stream>>>((const float4*)wt, 4194304, scal+0);
  k_qw   <<<dim3(16384), b256, 0, stream>>>(Bq, wt, scal+0);

  // ---- power iteration 1 ----
  k_prep_vct<<<dim3(64),  b256, 0, stream>>>(V0, VcTh, VcTm, VcTl);
  k_gv     <<<dim3(64,8), b256, 0, stream>>>(P, x, VcTh, VcTm, VcTl);
  k_gram   <<<dim3(64),   b256, 0, stream>>>(P, Gm);
  k_cholinv<<<dim3(1), dim3(256), 0, stream>>>(Gm, Li);
  k_applyq <<<dim3(128),  b256, 0, stream>>>(Ub, P, Li);
  k_prep_u <<<dim3(128),  b256, 0, stream>>>(Ub, Uh, Ul, UTh, UTm, UTl);
  k_gtu    <<<dim3(64,8), b256, 0, stream>>>(W, x, UTh, UTm, UTl);
  k_colnorm<<<dim3(64),   b256, 0, stream>>>(W, Sv);
  k_prep_vctn<<<dim3(64), b256, 0, stream>>>(W, Sv, VcTh, VcTm, VcTl);

  // ---- power iteration 2 ----
  k_zero   <<<dim3(2048), b256, 0, stream>>>(F, (int)nZero2);      // P, W, Gram
  k_gv     <<<dim3(64,8), b256, 0, stream>>>(P, x, VcTh, VcTm, VcTl);
  k_gram   <<<dim3(64),   b256, 0, stream>>>(P, Gm);
  k_cholinv<<<dim3(1), dim3(256), 0, stream>>>(Gm, Li);
  k_applyq <<<dim3(128),  b256, 0, stream>>>(Ub, P, Li);
  k_prep_u <<<dim3(128),  b256, 0, stream>>>(Ub, Uh, Ul, UTh, UTm, UTl);
  k_gtu    <<<dim3(64,8), b256, 0, stream>>>(W, x, UTh, UTm, UTl);
  k_colnorm<<<dim3(64),   b256, 0, stream>>>(W, Sv);               // Sv = S
  k_kv     <<<dim3(1024), b256, 0, stream>>>(KVTh, KVTl, W, Sv, scal+2);

  // ---- quantize factors + residual ----
  k_amax4<<<dim3(1024), b256, 0, stream>>>((const float4*)Ub, 131072, scal+1);
  k_qu   <<<dim3(2048), b256, 0, stream>>>(Aq, Ub, scal+1);
  k_qv   <<<dim3(64),   b256, 0, stream>>>(Vq, W, Sv, scal+2);
  k_res  <<<dim3(128,32), b256, 0, stream>>>(x, Uh, Ul, KVTh, KVTl, scal+3, Aq, 0);
  k_res  <<<dim3(128,32), b256, 0, stream>>>(x, Uh, Ul, KVTh, KVTl, scal+3, Aq, 1);

  // ---- low-rank fold + main GEMM ----
  k_m1  <<<dim3(64,8), b256, 0, stream>>>(M1, Vq, Bq);
  k_m2t <<<dim3(1024), b256, 0, stream>>>(Bq, M1, Sv, scal);
  k_gemm<<<dim3(16,32), dim3(512), 0, stream>>>(out, Aq, Bq, bias, scal);
}